// Round 13
// baseline (1164.343 us; speedup 1.0000x reference)
//
#include <hip/hip_runtime.h>
#include <math.h>

// ---------------- constants ----------------
constexpr float RADIUS     = 0.1125f;
constexpr float INV_RADIUS = 1.0f / RADIUS;
constexpr float DT         = 1.0f / 50.0f;
constexpr float FOPI       = 1.2732395447351628f; // 4/pi

// packed per-edge record: 32 B, two float4 loads
struct __align__(16) ERec {
  float fx, fy, fz, win;
  int   base, src, pad0, pad1;
};

// XCD-aware block->row swizzle (8 XCDs, round-robin dispatch): give each XCD a
// contiguous dst range so neighboring dsts (sharing ~90% of src rows) share L2.
__device__ __forceinline__ int xcd_swizzle(int b, int nb) {
  return (nb & 7) ? b : ((b & 7) * (nb >> 3) + (b >> 3));
}

// ---------------- prep: pos2, feats=[1,vel2] ----------------
__global__ __launch_bounds__(256) void k_prep(const float* __restrict__ pos,
                                              const float* __restrict__ vel,
                                              float* __restrict__ pos2,
                                              float* __restrict__ feats, int n) {
  int i = blockIdx.x * blockDim.x + threadIdx.x;
  if (i >= n) return;
  float vx = vel[i*3+0], vy = vel[i*3+1], vz = vel[i*3+2];
  float v2x = vx, v2y = vy + DT * (-9.81f), v2z = vz;
  pos2[i*3+0] = pos[i*3+0] + DT * 0.5f * (v2x + vx);
  pos2[i*3+1] = pos[i*3+1] + DT * 0.5f * (v2y + vy);
  pos2[i*3+2] = pos[i*3+2] + DT * 0.5f * (v2z + vz);
  feats[i*4+0] = 1.0f;
  feats[i*4+1] = v2x; feats[i*4+2] = v2y; feats[i*4+3] = v2z;
}

// ---------------- rowptr ----------------
__global__ __launch_bounds__(256) void k_rowptr(const int* __restrict__ ffdst, int Eff,
                                                const int* __restrict__ bfdst, int Ebf,
                                                int* __restrict__ rowff, int* __restrict__ rowbf,
                                                int n) {
  int d = blockIdx.x * blockDim.x + threadIdx.x;
  if (d > n) return;
  { int lo = 0, hi = Eff;
    while (lo < hi) { int mid = (lo + hi) >> 1; if (ffdst[mid] < d) lo = mid + 1; else hi = mid; }
    rowff[d] = lo; }
  { int lo = 0, hi = Ebf;
    while (lo < hi) { int mid = (lo + hi) >> 1; if (bfdst[mid] < d) lo = mid + 1; else hi = mid; }
    rowbf[d] = lo; }
}

// ---------------- per-edge geometry -> packed ERec ----------------
__global__ __launch_bounds__(256) void k_geom(const int* __restrict__ srcs,
                                              const int* __restrict__ dsts,
                                              const float* __restrict__ srcpos,
                                              const float* __restrict__ dstpos,
                                              ERec* __restrict__ geo, int E) {
  int e = blockIdx.x * blockDim.x + threadIdx.x;
  if (e >= E) return;
  int s = srcs[e], d = dsts[e];
  float rx = (srcpos[s*3+0] - dstpos[d*3+0]) * INV_RADIUS;
  float ry = (srcpos[s*3+1] - dstpos[d*3+1]) * INV_RADIUS;
  float rz = (srcpos[s*3+2] - dstpos[d*3+2]) * INV_RADIUS;
  float r2 = rx*rx + ry*ry + rz*rz;
  float t = 1.0f - r2;
  float win = t * t * t;
  win = fminf(fmaxf(win, 0.0f), 1.0f);
  float x = rx, y = ry, z = rz;
  float sq = r2;
  float norm = sqrtf(sq + 1e-24f);
  float xy_sq = x*x + y*y;
  bool zero = sq < 1e-12f;
  bool cone = 1.25f * z * z > xy_sq;
  float s_cone = sqrtf(3.0f * norm / (norm + fabsf(z) + 1e-12f));
  float s_side = norm / sqrtf(xy_sq + 1e-24f);
  float sgnz = (z > 0.0f) ? 1.0f : ((z < 0.0f) ? -1.0f : 0.0f);
  float xc = zero ? 0.0f : (cone ? x * s_cone : x * s_side);
  float yc = zero ? 0.0f : (cone ? y * s_cone : y * s_side);
  float zc = zero ? 0.0f : (cone ? sgnz * norm : 1.5f * z);
  float nxy_sq = xc*xc + yc*yc;
  float nxy = sqrtf(nxy_sq + 1e-24f);
  bool zero_xy = nxy_sq < 1e-12f;
  bool xbig = fabsf(xc) > fabsf(yc);
  float dx_ = (fabsf(xc) > 1e-12f) ? xc : 1.0f;
  float dy_ = (fabsf(yc) > 1e-12f) ? yc : 1.0f;
  float sgnx = (xc > 0.0f) ? 1.0f : ((xc < 0.0f) ? -1.0f : 0.0f);
  float sgny = (yc > 0.0f) ? 1.0f : ((yc < 0.0f) ? -1.0f : 0.0f);
  float tx = sgnx * nxy, ty = sgny * nxy;
  float xq = zero_xy ? 0.0f : (xbig ? tx : ty * FOPI * atanf(xc / dy_));
  float yq = zero_xy ? 0.0f : (xbig ? tx * FOPI * atanf(yc / dx_) : ty);
  float gx = (xq + 1.0f) * 1.5f;
  float gy = (yq + 1.0f) * 1.5f;
  float gz = (zc + 1.0f) * 1.5f;
  float g0x = fminf(fmaxf(floorf(gx), 0.0f), 2.0f);
  float g0y = fminf(fmaxf(floorf(gy), 0.0f), 2.0f);
  float g0z = fminf(fmaxf(floorf(gz), 0.0f), 2.0f);
  ERec g;
  g.fx = gx - g0x; g.fy = gy - g0y; g.fz = gz - g0z; g.win = win;
  g.base = (int)g0z * 16 + (int)g0y * 4 + (int)g0x;
  g.src = s; g.pad0 = 0; g.pad1 = 0;
  geo[e] = g;
}

// ---------------- layer0: lane=bin register-gather, ff/bf loops INTERLEAVED ----------------
// Two independent edge streams share the loop so both chains are in flight.
// Per-accumulator edge order unchanged -> bit-identical to R12.
__global__ __launch_bounds__(256) void k_layer0(const float* __restrict__ feats,
                                                const float* __restrict__ bfeats,
                                                const int* __restrict__ rowff,
                                                const ERec* __restrict__ gff,
                                                const int* __restrict__ rowbf,
                                                const ERec* __restrict__ gbf,
                                                const float* __restrict__ W0f, const float* __restrict__ b0f,
                                                const float* __restrict__ W0o, const float* __restrict__ b0o,
                                                const float* __restrict__ Wd0, const float* __restrict__ bd0,
                                                float* __restrict__ x0, int n) {
  __shared__ float Tf[4][256];   // [dst][bin*4+ch]
  __shared__ float To[4][256];   // [dst][bin*4+ch] (ch<3 used)
  int tid = threadIdx.x, lane = tid & 63, g = tid >> 6;
  int bsw = xcd_swizzle(blockIdx.x, gridDim.x);
  int dst = bsw * 4 + g;
  bool valid = dst < n;
  int bx = lane & 3, by = (lane >> 2) & 3, bz = lane >> 4;
  float a0 = 0, a1 = 0, a2 = 0, a3 = 0;   // ff accumulators (4 ch)
  float q0 = 0, q1 = 0, q2 = 0;           // bf accumulators (3 ch)
  int ffe0 = valid ? rowff[dst] : 0, ffe1 = valid ? rowff[dst+1] : 0;
  int bfe0 = valid ? rowbf[dst] : 0, bfe1 = valid ? rowbf[dst+1] : 0;
  // ff prefetch (depth-2)
  ERec rA, rB; float4 fA = make_float4(0,0,0,0), fB = fA;
  if (ffe0 + 0 < ffe1) { rA = gff[ffe0 + 0]; fA = *(const float4*)&feats[(size_t)rA.src*4]; }
  if (ffe0 + 1 < ffe1) { rB = gff[ffe0 + 1]; fB = *(const float4*)&feats[(size_t)rB.src*4]; }
  // bf prefetch (depth-2)
  ERec sA, sB; float gA0=0,gA1=0,gA2=0, gB0=0,gB1=0,gB2=0;
  if (bfe0 + 0 < bfe1) { sA = gbf[bfe0 + 0]; const float* p=&bfeats[(size_t)sA.src*3]; gA0=p[0]; gA1=p[1]; gA2=p[2]; }
  if (bfe0 + 1 < bfe1) { sB = gbf[bfe0 + 1]; const float* p=&bfeats[(size_t)sB.src*3]; gB0=p[0]; gB1=p[1]; gB2=p[2]; }
  int ei = ffe0, bi = bfe0;
  while (ei < ffe1 || bi < bfe1) {
    bool doF = ei < ffe1, doB = bi < bfe1;
    ERec rC; float4 fC = make_float4(0,0,0,0);
    if (ei + 2 < ffe1) { rC = gff[ei + 2]; fC = *(const float4*)&feats[(size_t)rC.src*4]; }
    ERec sC; float gC0=0,gC1=0,gC2=0;
    if (bi + 2 < bfe1) { sC = gbf[bi + 2]; const float* p=&bfeats[(size_t)sC.src*3]; gC0=p[0]; gC1=p[1]; gC2=p[2]; }
    if (doF) {
      int gx = rA.base & 3, gy = (rA.base >> 2) & 3, gz = rA.base >> 4;
      float wx = (bx == gx) ? (1.0f - rA.fx) : ((bx == gx + 1) ? rA.fx : 0.0f);
      float wy = (by == gy) ? (1.0f - rA.fy) : ((by == gy + 1) ? rA.fy : 0.0f);
      float wz = (bz == gz) ? (1.0f - rA.fz) : ((bz == gz + 1) ? rA.fz : 0.0f);
      float w = rA.win * wx * wy * wz;
      a0 += w * fA.x; a1 += w * fA.y; a2 += w * fA.z; a3 += w * fA.w;
      rA = rB; fA = fB; rB = rC; fB = fC;
      ++ei;
    }
    if (doB) {
      int gx = sA.base & 3, gy = (sA.base >> 2) & 3, gz = sA.base >> 4;
      float wx = (bx == gx) ? (1.0f - sA.fx) : ((bx == gx + 1) ? sA.fx : 0.0f);
      float wy = (by == gy) ? (1.0f - sA.fy) : ((by == gy + 1) ? sA.fy : 0.0f);
      float wz = (bz == gz) ? (1.0f - sA.fz) : ((bz == gz + 1) ? sA.fz : 0.0f);
      float w = sA.win * wx * wy * wz;
      q0 += w * gA0; q1 += w * gA1; q2 += w * gA2;
      sA = sB; gA0 = gB0; gA1 = gB1; gA2 = gB2;
      sB = sC; gB0 = gC0; gB1 = gC1; gB2 = gC2;
      ++bi;
    }
  }
  // park register T into LDS (one b128 each)
  *(float4*)&Tf[g][lane*4] = make_float4(a0, a1, a2, a3);
  *(float4*)&To[g][lane*4] = make_float4(q0, q1, q2, 0.0f);
  __syncthreads();
  // ---- GEMM: o = lane&31, halves over bins, broadcast LDS reads ----
  int o = lane & 31, h = lane >> 5;
  float accF = 0.0f, accO = 0.0f;
  const float* Tfg = Tf[g];
  const float* Tog = To[g];
  #pragma unroll 4
  for (int bin = h*32; bin < h*32 + 32; ++bin) {
    float4 t = *(const float4*)&Tfg[bin*4];
    const float* wf = W0f + bin*128 + o;
    accF += t.x*wf[0] + t.y*wf[32] + t.z*wf[64] + t.w*wf[96];
    float4 u = *(const float4*)&Tog[bin*4];
    const float* wo = W0o + bin*96 + o;
    accO += u.x*wo[0] + u.y*wo[32] + u.z*wo[64];
  }
  accF += __shfl_down(accF, 32, 64);
  accO += __shfl_down(accO, 32, 64);
  if (lane < 32 && valid) {
    float4 fdv = *(const float4*)&feats[(size_t)dst*4];
    float d0 = bd0[o] + fdv.x*Wd0[o] + fdv.y*Wd0[32+o] + fdv.z*Wd0[64+o] + fdv.w*Wd0[96+o];
    x0[(size_t)dst*96 + o]      = fmaxf(accO + b0o[o], 0.0f);
    x0[(size_t)dst*96 + 32 + o] = fmaxf(accF + b0f[o], 0.0f);
    x0[(size_t)dst*96 + 64 + o] = fmaxf(d0, 0.0f);
  }
}

// ---------------- scatter (R12 verbatim): T rows [T(64*CIN) | xin(CIN)] -> HBM ----------------
template<int CIN>
__global__ __launch_bounds__(128) void k_scatter(const float* __restrict__ xin,
                                                 const int* __restrict__ rowp,
                                                 const ERec* __restrict__ geo,
                                                 float* __restrict__ Tbuf,
                                                 int s0, int rows, int n) {
  constexpr int KTOT = 64 * CIN;
  constexpr int LD = KTOT + CIN;
  __shared__ float T[KTOT];
  int tid = threadIdx.x;
  for (int idx = tid; idx < KTOT; idx += 128) T[idx] = 0.0f;
  __syncthreads();
  int lrow = xcd_swizzle(blockIdx.x, gridDim.x);
  {
    int dzw = tid >> 6, lane = tid & 63;
    int dst = s0 + lrow;
    int e0 = 0, e1 = 0;
    if (lrow < rows && dst < n) { e0 = rowp[dst]; e1 = rowp[dst+1]; }
    if constexpr (CIN == 64) {
      int c = lane >> 4, q = lane & 15;
      int dx = c & 1, dy = (c >> 1) & 1;
      int coff = (dzw*16 + dy*4 + dx) * 64 + q*4;
      ERec rA, rB, rC;
      float4 a = make_float4(0,0,0,0), b = a;
      if (e0 + 0 < e1) rA = geo[e0 + 0];
      if (e0 + 1 < e1) rB = geo[e0 + 1];
      if (e0 + 2 < e1) rC = geo[e0 + 2];
      if (e0 + 0 < e1) a = *(const float4*)&xin[(size_t)rA.src*64 + q*4];
      if (e0 + 1 < e1) b = *(const float4*)&xin[(size_t)rB.src*64 + q*4];
      for (int e = e0; e < e1; ++e) {
        ERec rD;
        if (e + 3 < e1) rD = geo[e + 3];
        float4 cc = make_float4(0,0,0,0);
        if (e + 2 < e1) cc = *(const float4*)&xin[(size_t)rC.src*64 + q*4];
        float w = rA.win * (dzw ? rA.fz : 1.0f - rA.fz)
                         * (dx  ? rA.fx : 1.0f - rA.fx)
                         * (dy  ? rA.fy : 1.0f - rA.fy);
        float* p = &T[rA.base*64 + coff];
        float4 t = *(float4*)p;
        t.x += w*a.x; t.y += w*a.y; t.z += w*a.z; t.w += w*a.w;
        *(float4*)p = t;
        rA = rB; a = b; rB = rC; b = cc; rC = rD;
      }
    } else {
      bool act = lane < 48;
      int cq = lane / 24;
      int q  = lane - 24*cq;
      ERec rA, rB, rC;
      float4 a = make_float4(0,0,0,0), b = a;
      if (e0 + 0 < e1) rA = geo[e0 + 0];
      if (e0 + 1 < e1) rB = geo[e0 + 1];
      if (e0 + 2 < e1) rC = geo[e0 + 2];
      if (e0 + 0 < e1 && act) a = *(const float4*)&xin[(size_t)rA.src*96 + q*4];
      if (e0 + 1 < e1 && act) b = *(const float4*)&xin[(size_t)rB.src*96 + q*4];
      for (int e = e0; e < e1; ++e) {
        ERec rD;
        if (e + 3 < e1) rD = geo[e + 3];
        float4 cc = make_float4(0,0,0,0);
        if (e + 2 < e1 && act) cc = *(const float4*)&xin[(size_t)rC.src*96 + q*4];
        if (act) {
          float wz = rA.win * (dzw ? rA.fz : 1.0f - rA.fz);
          float wx0 = 1.0f - rA.fx, wx1 = rA.fx;
          float wy0 = 1.0f - rA.fy, wy1 = rA.fy;
          int tb = (rA.base + dzw*16)*96 + q*4;
          #pragma unroll
          for (int p = 0; p < 2; ++p) {
            int c = p*2 + cq;
            int dx = c & 1, dy = c >> 1;
            float w = wz * (dx ? wx1 : wx0) * (dy ? wy1 : wy0);
            float* ptr = &T[tb + (dy*4 + dx)*96];
            float4 t = *(float4*)ptr;
            t.x += w*a.x; t.y += w*a.y; t.z += w*a.z; t.w += w*a.w;
            *(float4*)ptr = t;
          }
        }
        rA = rB; a = b; rB = rC; b = cc; rC = rD;
      }
    }
  }
  __syncthreads();
  int dst = s0 + lrow;
  if (lrow < rows && dst < n) {
    float4* drow = (float4*)(Tbuf + (size_t)lrow * LD);
    const float4* srow = (const float4*)T;
    #pragma unroll 4
    for (int q = tid; q < KTOT/4; q += 128) drow[q] = srow[q];
    const float4* xr = (const float4*)(xin + (size_t)dst * CIN);
    if (tid < CIN/4) drow[KTOT/4 + tid] = xr[tid];
  }
}

// ---------------- split-K blocked GEMM (R12 verbatim, KSPLIT=8) ----------------
template<int CIN, int KSPLIT>
__global__ __launch_bounds__(128) void k_gemm_sk(const float* __restrict__ Tbuf,
                                                 const float* __restrict__ Wc,
                                                 const float* __restrict__ Wd,
                                                 float* __restrict__ P,
                                                 int rows, int n) {
  constexpr int KTOT = 64 * CIN;
  constexpr int LD = KTOT + CIN;
  constexpr int TILES = LD / 32;
  constexpr int TPC = (TILES + KSPLIT - 1) / KSPLIT;
  __shared__ float Al[32][32];
  __shared__ float Bl[32*64];
  int tid = threadIdx.x;
  int tx = tid & 15, ty = tid >> 4;
  int r = tid & 31, kb = (tid >> 5) * 8;
  int m0 = blockIdx.x * 32;
  int chunk = blockIdx.y;
  int cbeg = chunk * TPC * 32;
  int cend = (chunk + 1) * TPC * 32; if (cend > LD) cend = LD;
  const float* Abase = Tbuf + (size_t)m0 * LD + (size_t)r * LD;
  float C[4][4] = {{0}};
  float4 aN0, aN1, bN0, bN1, bN2, bN3;
  auto loadnext = [&](int c0) {
    const float* ap = Abase + c0 + kb;
    aN0 = *(const float4*)ap;
    aN1 = *(const float4*)(ap + 4);
    const float4* bs = (const float4*)((c0 < KTOT) ? (Wc + (size_t)c0 * 64)
                                                   : (Wd + (size_t)(c0 - KTOT) * 64));
    bN0 = bs[tid]; bN1 = bs[tid+128]; bN2 = bs[tid+256]; bN3 = bs[tid+384];
  };
  if (cbeg >= cend) return;
  loadnext(cbeg);
  for (int c0 = cbeg; c0 < cend; c0 += 32) {
    Al[kb+0][r] = aN0.x; Al[kb+1][r] = aN0.y; Al[kb+2][r] = aN0.z; Al[kb+3][r] = aN0.w;
    Al[kb+4][r] = aN1.x; Al[kb+5][r] = aN1.y; Al[kb+6][r] = aN1.z; Al[kb+7][r] = aN1.w;
    float4* bl4 = (float4*)Bl;
    bl4[tid] = bN0; bl4[tid+128] = bN1; bl4[tid+256] = bN2; bl4[tid+384] = bN3;
    __syncthreads();
    if (c0 + 32 < cend) loadnext(c0 + 32);
    #pragma unroll 8
    for (int k = 0; k < 32; ++k) {
      float4 av = *(const float4*)&Al[k][ty*4];
      float4 bv = *(const float4*)&Bl[k*64 + tx*4];
      C[0][0] += av.x*bv.x; C[0][1] += av.x*bv.y; C[0][2] += av.x*bv.z; C[0][3] += av.x*bv.w;
      C[1][0] += av.y*bv.x; C[1][1] += av.y*bv.y; C[1][2] += av.y*bv.z; C[1][3] += av.y*bv.w;
      C[2][0] += av.z*bv.x; C[2][1] += av.z*bv.y; C[2][2] += av.z*bv.z; C[2][3] += av.z*bv.w;
      C[3][0] += av.w*bv.x; C[3][1] += av.w*bv.y; C[3][2] += av.w*bv.z; C[3][3] += av.w*bv.w;
    }
    __syncthreads();
  }
  float* Pc = P + (size_t)chunk * n * 64;
  #pragma unroll
  for (int i = 0; i < 4; ++i) {
    int lrow = m0 + ty*4 + i;
    if (lrow < rows) {
      float4 v; v.x = C[i][0]; v.y = C[i][1]; v.z = C[i][2]; v.w = C[i][3];
      ((float4*)(Pc + (size_t)lrow * 64))[tx] = v;
    }
  }
}

// ---------------- epilogue (R12 verbatim) ----------------
template<int KSPLIT>
__global__ __launch_bounds__(256) void k_epi(const float* __restrict__ P,
                                             const float* __restrict__ bc,
                                             const float* __restrict__ bd,
                                             const float* __restrict__ hres,
                                             float* __restrict__ hout,
                                             float* __restrict__ xout,
                                             int s0, int rows, int n) {
  int idx = blockIdx.x * 256 + threadIdx.x;
  if (idx >= rows * 16) return;
  int lrow = idx >> 4, c4 = idx & 15;
  int dst = s0 + lrow;
  if (dst >= n) return;
  float4 v = ((const float4*)(P + (size_t)lrow * 64))[c4];
  #pragma unroll
  for (int k = 1; k < KSPLIT; ++k) {
    float4 p = ((const float4*)(P + ((size_t)k * n + lrow) * 64))[c4];
    v.x += p.x; v.y += p.y; v.z += p.z; v.w += p.w;
  }
  float4 b1 = ((const float4*)bc)[c4];
  float4 b2 = ((const float4*)bd)[c4];
  v.x += b1.x + b2.x; v.y += b1.y + b2.y; v.z += b1.z + b2.z; v.w += b1.w + b2.w;
  if (hres) {
    float4 h = ((const float4*)hres)[(size_t)dst*16 + c4];
    v.x += h.x; v.y += h.y; v.z += h.z; v.w += h.w;
  }
  if (hout) ((float4*)hout)[(size_t)dst*16 + c4] = v;
  float4 rl;
  rl.x = fmaxf(v.x, 0.f); rl.y = fmaxf(v.y, 0.f);
  rl.z = fmaxf(v.z, 0.f); rl.w = fmaxf(v.w, 0.f);
  ((float4*)xout)[(size_t)dst*16 + c4] = rl;
}

// ---------------- layer3 part: 2 blocks/dst, each half of the edge list ----------------
// Scatter body = R9 verbatim over [eb,ee); dot = R12 verbatim; partial written to Ppart.
// Dot is linear so partial dots sum (regrouping-class change, same as KSPLIT).
__global__ __launch_bounds__(256) void k_l3part(const float* __restrict__ xin,
                                                const int* __restrict__ rowp,
                                                const ERec* __restrict__ geo,
                                                const float* __restrict__ Wc,
                                                const float* __restrict__ Wd,
                                                float* __restrict__ Ppart, int n) {
  __shared__ float T[4096];
  __shared__ float red[4][3];
  int tid = threadIdx.x, lane = tid & 63, wave = tid >> 6;
  int sw = xcd_swizzle(blockIdx.x, gridDim.x);
  int dst = sw >> 1, half = sw & 1;   // both halves of a dst on same XCD
  for (int idx = tid; idx < 4096; idx += 256) T[idx] = 0.0f;
  __syncthreads();
  bool valid = dst < n;
  // ---- scatter phase over this block's edge half ----
  if (tid < 128) {
    int dzw = tid >> 6, lane2 = tid & 63;
    int e0 = 0, e1 = 0;
    if (valid) { e0 = rowp[dst]; e1 = rowp[dst+1]; }
    int cnt = e1 - e0;
    int emid = e0 + ((cnt + 1) >> 1);
    int eb = half ? emid : e0;
    int ee = half ? e1 : emid;
    int c = lane2 >> 4, q = lane2 & 15;
    int dx = c & 1, dy = (c >> 1) & 1;
    int coff = (dzw*16 + dy*4 + dx) * 64 + q*4;
    ERec rA, rB, rC;
    float4 a = make_float4(0,0,0,0), b = a;
    if (eb + 0 < ee) rA = geo[eb + 0];
    if (eb + 1 < ee) rB = geo[eb + 1];
    if (eb + 2 < ee) rC = geo[eb + 2];
    if (eb + 0 < ee) a = *(const float4*)&xin[(size_t)rA.src*64 + q*4];
    if (eb + 1 < ee) b = *(const float4*)&xin[(size_t)rB.src*64 + q*4];
    for (int e = eb; e < ee; ++e) {
      ERec rD;
      if (e + 3 < ee) rD = geo[e + 3];
      float4 cc = make_float4(0,0,0,0);
      if (e + 2 < ee) cc = *(const float4*)&xin[(size_t)rC.src*64 + q*4];
      float w = rA.win * (dzw ? rA.fz : 1.0f - rA.fz)
                       * (dx  ? rA.fx : 1.0f - rA.fx)
                       * (dy  ? rA.fy : 1.0f - rA.fy);
      float* p = &T[rA.base*64 + coff];
      float4 t = *(float4*)p;
      t.x += w*a.x; t.y += w*a.y; t.z += w*a.z; t.w += w*a.w;
      *(float4*)p = t;
      rA = rB; a = b; rB = rC; b = cc; rC = rD;
    }
  }
  __syncthreads();
  // ---- dot phase (R12 verbatim; Wd/xin tail only in half 0) ----
  float a0 = 0, a1 = 0, a2 = 0;
  if (valid) {
    #pragma unroll
    for (int c2 = 0; c2 < 4; ++c2) {
      int k = c2*1024 + tid*4;
      float4 tv = *(const float4*)&T[k];
      float w00 = Wc[(size_t)(k+0)*3+0], w01 = Wc[(size_t)(k+1)*3+0],
            w02 = Wc[(size_t)(k+2)*3+0], w03 = Wc[(size_t)(k+3)*3+0];
      float w10 = Wc[(size_t)(k+0)*3+1], w11 = Wc[(size_t)(k+1)*3+1],
            w12 = Wc[(size_t)(k+2)*3+1], w13 = Wc[(size_t)(k+3)*3+1];
      float w20 = Wc[(size_t)(k+0)*3+2], w21 = Wc[(size_t)(k+1)*3+2],
            w22 = Wc[(size_t)(k+2)*3+2], w23 = Wc[(size_t)(k+3)*3+2];
      a0 += tv.x*w00 + tv.y*w01 + tv.z*w02 + tv.w*w03;
      a1 += tv.x*w10 + tv.y*w11 + tv.z*w12 + tv.w*w13;
      a2 += tv.x*w20 + tv.y*w21 + tv.z*w22 + tv.w*w23;
    }
    if (half == 0 && tid < 16) {
      int k = tid*4;
      float4 tv = *(const float4*)&xin[(size_t)dst*64 + k];
      float w00 = Wd[(k+0)*3+0], w01 = Wd[(k+1)*3+0], w02 = Wd[(k+2)*3+0], w03 = Wd[(k+3)*3+0];
      float w10 = Wd[(k+0)*3+1], w11 = Wd[(k+1)*3+1], w12 = Wd[(k+2)*3+1], w13 = Wd[(k+3)*3+1];
      float w20 = Wd[(k+0)*3+2], w21 = Wd[(k+1)*3+2], w22 = Wd[(k+2)*3+2], w23 = Wd[(k+3)*3+2];
      a0 += tv.x*w00 + tv.y*w01 + tv.z*w02 + tv.w*w03;
      a1 += tv.x*w10 + tv.y*w11 + tv.z*w12 + tv.w*w13;
      a2 += tv.x*w20 + tv.y*w21 + tv.z*w22 + tv.w*w23;
    }
  }
  #pragma unroll
  for (int off = 32; off > 0; off >>= 1) {
    a0 += __shfl_down(a0, off, 64);
    a1 += __shfl_down(a1, off, 64);
    a2 += __shfl_down(a2, off, 64);
  }
  if (lane == 0) { red[wave][0] = a0; red[wave][1] = a1; red[wave][2] = a2; }
  __syncthreads();
  if (tid < 3 && valid) {
    float p = red[0][tid] + red[1][tid] + red[2][tid] + red[3][tid];
    Ppart[((size_t)dst*2 + half)*4 + tid] = p;
  }
}

// ---------------- layer3 merge: sum halves + bias, integrate ----------------
__global__ __launch_bounds__(256) void k_l3merge(const float* __restrict__ Ppart,
                                                 const float* __restrict__ bc,
                                                 const float* __restrict__ bd,
                                                 const float* __restrict__ pos,
                                                 const float* __restrict__ pos2,
                                                 float* __restrict__ out, int n) {
  int idx = blockIdx.x * 256 + threadIdx.x;
  if (idx >= n * 3) return;
  int dst = idx / 3, ch = idx - dst * 3;
  float h3 = Ppart[((size_t)dst*2 + 0)*4 + ch] + Ppart[((size_t)dst*2 + 1)*4 + ch]
           + bc[ch] + bd[ch];
  float pn = pos2[dst*3 + ch] + h3 * (1.0f / 128.0f);
  float vn = (pn - pos[dst*3 + ch]) * (1.0f / DT);
  out[(size_t)dst*6 + ch] = pn;
  out[(size_t)dst*6 + 3 + ch] = vn;
}

// ---------------- host ----------------
extern "C" void kernel_launch(void* const* d_in, const int* in_sizes, int n_in,
                              void* d_out, int out_size, void* d_ws, size_t ws_size,
                              hipStream_t stream) {
  const float* pos    = (const float*)d_in[0];
  const float* vel    = (const float*)d_in[1];
  const float* box    = (const float*)d_in[2];
  const float* bfeats = (const float*)d_in[3];
  const int*   ffsrc  = (const int*)d_in[4];
  const int*   ffdst  = (const int*)d_in[5];
  const int*   bfsrc  = (const int*)d_in[6];
  const int*   bfdst  = (const int*)d_in[7];
  const float* W0f = (const float*)d_in[8];
  const float* b0f = (const float*)d_in[9];
  const float* W0o = (const float*)d_in[10];
  const float* b0o = (const float*)d_in[11];
  const float* Wd0 = (const float*)d_in[12];
  const float* bd0 = (const float*)d_in[13];
  const float* Wc1 = (const float*)d_in[14];
  const float* bc1 = (const float*)d_in[15];
  const float* Wd1 = (const float*)d_in[16];
  const float* bd1 = (const float*)d_in[17];
  const float* Wc2 = (const float*)d_in[18];
  const float* bc2 = (const float*)d_in[19];
  const float* Wd2 = (const float*)d_in[20];
  const float* bd2 = (const float*)d_in[21];
  const float* Wc3 = (const float*)d_in[22];
  const float* bc3 = (const float*)d_in[23];
  const float* Wd3 = (const float*)d_in[24];
  const float* bd3 = (const float*)d_in[25];

  int n   = in_sizes[0] / 3;
  int Eff = in_sizes[4];
  int Ebf = in_sizes[6];
  float* out = (float*)d_out;

  constexpr int KSPLIT = 8;

  char* w = (char*)d_ws;
  size_t used = 0;
  auto alloc = [&](size_t bytes) -> char* {
    char* p = w + used; used += (bytes + 255) & ~size_t(255); return p;
  };
  float* pos2  = (float*)alloc((size_t)n*3*4);
  float* feats = (float*)alloc((size_t)n*4*4);
  float* x0    = (float*)alloc((size_t)n*96*4);
  float* h1    = (float*)alloc((size_t)n*64*4);
  float* x1    = (float*)alloc((size_t)n*64*4);
  float* x2    = (float*)alloc((size_t)n*64*4);
  int*   rowff = (int*)alloc((size_t)(n+1)*4);
  int*   rowbf = (int*)alloc((size_t)(n+1)*4);
  ERec*  gff   = (ERec*)alloc((size_t)Eff*sizeof(ERec));
  ERec*  gbf   = (ERec*)alloc((size_t)Ebf*sizeof(ERec));
  float* Pbuf  = (float*)alloc((size_t)KSPLIT*n*64*4);
  float* Ppart = (float*)alloc((size_t)n*2*4*4);
  float* Tbuf  = (float*)(w + used);
  size_t rem   = (ws_size > used) ? (ws_size - used) : 0;

  constexpr int LD1 = 64*96 + 96;   // 6240
  constexpr int LD2 = 64*64 + 64;   // 4160
  auto cap_rows = [&](int ld) -> int {
    size_t cr = rem / ((size_t)ld * 4);
    if (cr > (size_t)n) cr = n;
    int c = (int)cr & ~63;
    if (c < 64) c = 64;
    return c;
  };
  int cap1 = cap_rows(LD1);
  int cap2 = cap_rows(LD2);

  k_prep<<<(n+255)/256, 256, 0, stream>>>(pos, vel, pos2, feats, n);
  k_rowptr<<<(n+256)/256, 256, 0, stream>>>(ffdst, Eff, bfdst, Ebf, rowff, rowbf, n);
  k_geom<<<(Eff+255)/256, 256, 0, stream>>>(ffsrc, ffdst, pos2, pos2, gff, Eff);
  k_geom<<<(Ebf+255)/256, 256, 0, stream>>>(bfsrc, bfdst, box,  pos2, gbf, Ebf);
  k_layer0<<<(n+3)/4, 256, 0, stream>>>(feats, bfeats, rowff, gff, rowbf, gbf,
                                        W0f, b0f, W0o, b0o, Wd0, bd0, x0, n);
  // layer1: CIN=96
  for (int s = 0; s < n; s += cap1) {
    int rows = (n - s < cap1) ? (n - s) : cap1;
    k_scatter<96><<<rows, 128, 0, stream>>>(x0, rowff, gff, Tbuf, s, rows, n);
    k_gemm_sk<96,KSPLIT><<<dim3((rows+31)/32, KSPLIT), 128, 0, stream>>>(
        Tbuf, Wc1, Wd1, Pbuf, rows, n);
    k_epi<KSPLIT><<<(rows*16+255)/256, 256, 0, stream>>>(
        Pbuf, bc1, bd1, nullptr, h1, x1, s, rows, n);
  }
  // layer2: CIN=64, residual h1
  for (int s = 0; s < n; s += cap2) {
    int rows = (n - s < cap2) ? (n - s) : cap2;
    k_scatter<64><<<rows, 128, 0, stream>>>(x1, rowff, gff, Tbuf, s, rows, n);
    k_gemm_sk<64,KSPLIT><<<dim3((rows+31)/32, KSPLIT), 128, 0, stream>>>(
        Tbuf, Wc2, Wd2, Pbuf, rows, n);
    k_epi<KSPLIT><<<(rows*16+255)/256, 256, 0, stream>>>(
        Pbuf, bc2, bd2, h1, nullptr, x2, s, rows, n);
  }
  // layer3: edge-split fused scatter+dot (2 blocks/dst) + merge/integrate
  k_l3part<<<2*n, 256, 0, stream>>>(x2, rowff, gff, Wc3, Wd3, Ppart, n);
  k_l3merge<<<(3*n+255)/256, 256, 0, stream>>>(Ppart, bc3, bd3, pos, pos2, out, n);
}

// Round 14
// 1164.045 us; speedup vs baseline: 1.0003x; 1.0003x over previous
//
#include <hip/hip_runtime.h>
#include <math.h>

// ---------------- constants ----------------
constexpr float RADIUS     = 0.1125f;
constexpr float INV_RADIUS = 1.0f / RADIUS;
constexpr float DT         = 1.0f / 50.0f;
constexpr float FOPI       = 1.2732395447351628f; // 4/pi

// packed per-edge record: 32 B, two float4 loads
struct __align__(16) ERec {
  float fx, fy, fz, win;
  int   base, src, pad0, pad1;
};

// XCD-aware block->row swizzle (8 XCDs, round-robin dispatch): give each XCD a
// contiguous dst range so neighboring dsts (sharing ~90% of src rows) share L2.
__device__ __forceinline__ int xcd_swizzle(int b, int nb) {
  return (nb & 7) ? b : ((b & 7) * (nb >> 3) + (b >> 3));
}

// ---------------- prep: pos2, feats=[1,vel2] ----------------
__global__ __launch_bounds__(256) void k_prep(const float* __restrict__ pos,
                                              const float* __restrict__ vel,
                                              float* __restrict__ pos2,
                                              float* __restrict__ feats, int n) {
  int i = blockIdx.x * blockDim.x + threadIdx.x;
  if (i >= n) return;
  float vx = vel[i*3+0], vy = vel[i*3+1], vz = vel[i*3+2];
  float v2x = vx, v2y = vy + DT * (-9.81f), v2z = vz;
  pos2[i*3+0] = pos[i*3+0] + DT * 0.5f * (v2x + vx);
  pos2[i*3+1] = pos[i*3+1] + DT * 0.5f * (v2y + vy);
  pos2[i*3+2] = pos[i*3+2] + DT * 0.5f * (v2z + vz);
  feats[i*4+0] = 1.0f;
  feats[i*4+1] = v2x; feats[i*4+2] = v2y; feats[i*4+3] = v2z;
}

// ---------------- rowptr ----------------
__global__ __launch_bounds__(256) void k_rowptr(const int* __restrict__ ffdst, int Eff,
                                                const int* __restrict__ bfdst, int Ebf,
                                                int* __restrict__ rowff, int* __restrict__ rowbf,
                                                int n) {
  int d = blockIdx.x * blockDim.x + threadIdx.x;
  if (d > n) return;
  { int lo = 0, hi = Eff;
    while (lo < hi) { int mid = (lo + hi) >> 1; if (ffdst[mid] < d) lo = mid + 1; else hi = mid; }
    rowff[d] = lo; }
  { int lo = 0, hi = Ebf;
    while (lo < hi) { int mid = (lo + hi) >> 1; if (bfdst[mid] < d) lo = mid + 1; else hi = mid; }
    rowbf[d] = lo; }
}

// ---------------- per-edge geometry -> packed ERec ----------------
__global__ __launch_bounds__(256) void k_geom(const int* __restrict__ srcs,
                                              const int* __restrict__ dsts,
                                              const float* __restrict__ srcpos,
                                              const float* __restrict__ dstpos,
                                              ERec* __restrict__ geo, int E) {
  int e = blockIdx.x * blockDim.x + threadIdx.x;
  if (e >= E) return;
  int s = srcs[e], d = dsts[e];
  float rx = (srcpos[s*3+0] - dstpos[d*3+0]) * INV_RADIUS;
  float ry = (srcpos[s*3+1] - dstpos[d*3+1]) * INV_RADIUS;
  float rz = (srcpos[s*3+2] - dstpos[d*3+2]) * INV_RADIUS;
  float r2 = rx*rx + ry*ry + rz*rz;
  float t = 1.0f - r2;
  float win = t * t * t;
  win = fminf(fmaxf(win, 0.0f), 1.0f);
  float x = rx, y = ry, z = rz;
  float sq = r2;
  float norm = sqrtf(sq + 1e-24f);
  float xy_sq = x*x + y*y;
  bool zero = sq < 1e-12f;
  bool cone = 1.25f * z * z > xy_sq;
  float s_cone = sqrtf(3.0f * norm / (norm + fabsf(z) + 1e-12f));
  float s_side = norm / sqrtf(xy_sq + 1e-24f);
  float sgnz = (z > 0.0f) ? 1.0f : ((z < 0.0f) ? -1.0f : 0.0f);
  float xc = zero ? 0.0f : (cone ? x * s_cone : x * s_side);
  float yc = zero ? 0.0f : (cone ? y * s_cone : y * s_side);
  float zc = zero ? 0.0f : (cone ? sgnz * norm : 1.5f * z);
  float nxy_sq = xc*xc + yc*yc;
  float nxy = sqrtf(nxy_sq + 1e-24f);
  bool zero_xy = nxy_sq < 1e-12f;
  bool xbig = fabsf(xc) > fabsf(yc);
  float dx_ = (fabsf(xc) > 1e-12f) ? xc : 1.0f;
  float dy_ = (fabsf(yc) > 1e-12f) ? yc : 1.0f;
  float sgnx = (xc > 0.0f) ? 1.0f : ((xc < 0.0f) ? -1.0f : 0.0f);
  float sgny = (yc > 0.0f) ? 1.0f : ((yc < 0.0f) ? -1.0f : 0.0f);
  float tx = sgnx * nxy, ty = sgny * nxy;
  float xq = zero_xy ? 0.0f : (xbig ? tx : ty * FOPI * atanf(xc / dy_));
  float yq = zero_xy ? 0.0f : (xbig ? tx * FOPI * atanf(yc / dx_) : ty);
  float gx = (xq + 1.0f) * 1.5f;
  float gy = (yq + 1.0f) * 1.5f;
  float gz = (zc + 1.0f) * 1.5f;
  float g0x = fminf(fmaxf(floorf(gx), 0.0f), 2.0f);
  float g0y = fminf(fmaxf(floorf(gy), 0.0f), 2.0f);
  float g0z = fminf(fmaxf(floorf(gz), 0.0f), 2.0f);
  ERec g;
  g.fx = gx - g0x; g.fy = gy - g0y; g.fz = gz - g0z; g.win = win;
  g.base = (int)g0z * 16 + (int)g0y * 4 + (int)g0x;
  g.src = s; g.pad0 = 0; g.pad1 = 0;
  geo[e] = g;
}

// ---------------- layer0: lane=bin register-gather (R12 verbatim) ----------------
__global__ __launch_bounds__(256) void k_layer0(const float* __restrict__ feats,
                                                const float* __restrict__ bfeats,
                                                const int* __restrict__ rowff,
                                                const ERec* __restrict__ gff,
                                                const int* __restrict__ rowbf,
                                                const ERec* __restrict__ gbf,
                                                const float* __restrict__ W0f, const float* __restrict__ b0f,
                                                const float* __restrict__ W0o, const float* __restrict__ b0o,
                                                const float* __restrict__ Wd0, const float* __restrict__ bd0,
                                                float* __restrict__ x0, int n) {
  __shared__ float Tf[4][256];   // [dst][bin*4+ch]
  __shared__ float To[4][256];   // [dst][bin*4+ch] (ch<3 used)
  int tid = threadIdx.x, lane = tid & 63, g = tid >> 6;
  int bsw = xcd_swizzle(blockIdx.x, gridDim.x);
  int dst = bsw * 4 + g;
  bool valid = dst < n;
  int bx = lane & 3, by = (lane >> 2) & 3, bz = lane >> 4;
  float a0 = 0, a1 = 0, a2 = 0, a3 = 0;   // ff accumulators (4 ch)
  float q0 = 0, q1 = 0, q2 = 0;           // bf accumulators (3 ch)
  // ---- ff edges (depth-2 prefetch) ----
  {
    int e0 = valid ? rowff[dst] : 0, e1 = valid ? rowff[dst+1] : 0;
    ERec rA, rB; float4 fA = make_float4(0,0,0,0), fB = fA;
    if (e0 + 0 < e1) { rA = gff[e0 + 0]; fA = *(const float4*)&feats[(size_t)rA.src*4]; }
    if (e0 + 1 < e1) { rB = gff[e0 + 1]; fB = *(const float4*)&feats[(size_t)rB.src*4]; }
    for (int e = e0; e < e1; ++e) {
      ERec rC; float4 fC = make_float4(0,0,0,0);
      if (e + 2 < e1) { rC = gff[e + 2]; fC = *(const float4*)&feats[(size_t)rC.src*4]; }
      int gx = rA.base & 3, gy = (rA.base >> 2) & 3, gz = rA.base >> 4;
      float wx = (bx == gx) ? (1.0f - rA.fx) : ((bx == gx + 1) ? rA.fx : 0.0f);
      float wy = (by == gy) ? (1.0f - rA.fy) : ((by == gy + 1) ? rA.fy : 0.0f);
      float wz = (bz == gz) ? (1.0f - rA.fz) : ((bz == gz + 1) ? rA.fz : 0.0f);
      float w = rA.win * wx * wy * wz;
      a0 += w * fA.x; a1 += w * fA.y; a2 += w * fA.z; a3 += w * fA.w;
      rA = rB; fA = fB; rB = rC; fB = fC;
    }
  }
  // ---- bf edges ----
  {
    int e0 = valid ? rowbf[dst] : 0, e1 = valid ? rowbf[dst+1] : 0;
    ERec rA, rB; float fA0=0,fA1=0,fA2=0, fB0=0,fB1=0,fB2=0;
    if (e0 + 0 < e1) { rA = gbf[e0 + 0]; const float* p=&bfeats[(size_t)rA.src*3]; fA0=p[0]; fA1=p[1]; fA2=p[2]; }
    if (e0 + 1 < e1) { rB = gbf[e0 + 1]; const float* p=&bfeats[(size_t)rB.src*3]; fB0=p[0]; fB1=p[1]; fB2=p[2]; }
    for (int e = e0; e < e1; ++e) {
      ERec rC; float fC0=0,fC1=0,fC2=0;
      if (e + 2 < e1) { rC = gbf[e + 2]; const float* p=&bfeats[(size_t)rC.src*3]; fC0=p[0]; fC1=p[1]; fC2=p[2]; }
      int gx = rA.base & 3, gy = (rA.base >> 2) & 3, gz = rA.base >> 4;
      float wx = (bx == gx) ? (1.0f - rA.fx) : ((bx == gx + 1) ? rA.fx : 0.0f);
      float wy = (by == gy) ? (1.0f - rA.fy) : ((by == gy + 1) ? rA.fy : 0.0f);
      float wz = (bz == gz) ? (1.0f - rA.fz) : ((bz == gz + 1) ? rA.fz : 0.0f);
      float w = rA.win * wx * wy * wz;
      q0 += w * fA0; q1 += w * fA1; q2 += w * fA2;
      rA = rB; fA0 = fB0; fA1 = fB1; fA2 = fB2;
      rB = rC; fB0 = fC0; fB1 = fC1; fB2 = fC2;
    }
  }
  // park register T into LDS (one b128 each)
  *(float4*)&Tf[g][lane*4] = make_float4(a0, a1, a2, a3);
  *(float4*)&To[g][lane*4] = make_float4(q0, q1, q2, 0.0f);
  __syncthreads();
  // ---- GEMM: o = lane&31, halves over bins, broadcast LDS reads ----
  int o = lane & 31, h = lane >> 5;
  float accF = 0.0f, accO = 0.0f;
  const float* Tfg = Tf[g];
  const float* Tog = To[g];
  #pragma unroll 4
  for (int bin = h*32; bin < h*32 + 32; ++bin) {
    float4 t = *(const float4*)&Tfg[bin*4];
    const float* wf = W0f + bin*128 + o;
    accF += t.x*wf[0] + t.y*wf[32] + t.z*wf[64] + t.w*wf[96];
    float4 u = *(const float4*)&Tog[bin*4];
    const float* wo = W0o + bin*96 + o;
    accO += u.x*wo[0] + u.y*wo[32] + u.z*wo[64];
  }
  accF += __shfl_down(accF, 32, 64);
  accO += __shfl_down(accO, 32, 64);
  if (lane < 32 && valid) {
    float4 fdv = *(const float4*)&feats[(size_t)dst*4];
    float d0 = bd0[o] + fdv.x*Wd0[o] + fdv.y*Wd0[32+o] + fdv.z*Wd0[64+o] + fdv.w*Wd0[96+o];
    x0[(size_t)dst*96 + o]      = fmaxf(accO + b0o[o], 0.0f);
    x0[(size_t)dst*96 + 32 + o] = fmaxf(accF + b0f[o], 0.0f);
    x0[(size_t)dst*96 + 64 + o] = fmaxf(d0, 0.0f);
  }
}

// ---------------- scatter (R12 verbatim): T rows [T(64*CIN) | xin(CIN)] -> HBM ----------------
template<int CIN>
__global__ __launch_bounds__(128) void k_scatter(const float* __restrict__ xin,
                                                 const int* __restrict__ rowp,
                                                 const ERec* __restrict__ geo,
                                                 float* __restrict__ Tbuf,
                                                 int s0, int rows, int n) {
  constexpr int KTOT = 64 * CIN;
  constexpr int LD = KTOT + CIN;
  __shared__ float T[KTOT];
  int tid = threadIdx.x;
  for (int idx = tid; idx < KTOT; idx += 128) T[idx] = 0.0f;
  __syncthreads();
  int lrow = xcd_swizzle(blockIdx.x, gridDim.x);
  {
    int dzw = tid >> 6, lane = tid & 63;
    int dst = s0 + lrow;
    int e0 = 0, e1 = 0;
    if (lrow < rows && dst < n) { e0 = rowp[dst]; e1 = rowp[dst+1]; }
    if constexpr (CIN == 64) {
      int c = lane >> 4, q = lane & 15;
      int dx = c & 1, dy = (c >> 1) & 1;
      int coff = (dzw*16 + dy*4 + dx) * 64 + q*4;
      ERec rA, rB, rC;
      float4 a = make_float4(0,0,0,0), b = a;
      if (e0 + 0 < e1) rA = geo[e0 + 0];
      if (e0 + 1 < e1) rB = geo[e0 + 1];
      if (e0 + 2 < e1) rC = geo[e0 + 2];
      if (e0 + 0 < e1) a = *(const float4*)&xin[(size_t)rA.src*64 + q*4];
      if (e0 + 1 < e1) b = *(const float4*)&xin[(size_t)rB.src*64 + q*4];
      for (int e = e0; e < e1; ++e) {
        ERec rD;
        if (e + 3 < e1) rD = geo[e + 3];
        float4 cc = make_float4(0,0,0,0);
        if (e + 2 < e1) cc = *(const float4*)&xin[(size_t)rC.src*64 + q*4];
        float w = rA.win * (dzw ? rA.fz : 1.0f - rA.fz)
                         * (dx  ? rA.fx : 1.0f - rA.fx)
                         * (dy  ? rA.fy : 1.0f - rA.fy);
        float* p = &T[rA.base*64 + coff];
        float4 t = *(float4*)p;
        t.x += w*a.x; t.y += w*a.y; t.z += w*a.z; t.w += w*a.w;
        *(float4*)p = t;
        rA = rB; a = b; rB = rC; b = cc; rC = rD;
      }
    } else {
      bool act = lane < 48;
      int cq = lane / 24;
      int q  = lane - 24*cq;
      ERec rA, rB, rC;
      float4 a = make_float4(0,0,0,0), b = a;
      if (e0 + 0 < e1) rA = geo[e0 + 0];
      if (e0 + 1 < e1) rB = geo[e0 + 1];
      if (e0 + 2 < e1) rC = geo[e0 + 2];
      if (e0 + 0 < e1 && act) a = *(const float4*)&xin[(size_t)rA.src*96 + q*4];
      if (e0 + 1 < e1 && act) b = *(const float4*)&xin[(size_t)rB.src*96 + q*4];
      for (int e = e0; e < e1; ++e) {
        ERec rD;
        if (e + 3 < e1) rD = geo[e + 3];
        float4 cc = make_float4(0,0,0,0);
        if (e + 2 < e1 && act) cc = *(const float4*)&xin[(size_t)rC.src*96 + q*4];
        if (act) {
          float wz = rA.win * (dzw ? rA.fz : 1.0f - rA.fz);
          float wx0 = 1.0f - rA.fx, wx1 = rA.fx;
          float wy0 = 1.0f - rA.fy, wy1 = rA.fy;
          int tb = (rA.base + dzw*16)*96 + q*4;
          #pragma unroll
          for (int p = 0; p < 2; ++p) {
            int c = p*2 + cq;
            int dx = c & 1, dy = c >> 1;
            float w = wz * (dx ? wx1 : wx0) * (dy ? wy1 : wy0);
            float* ptr = &T[tb + (dy*4 + dx)*96];
            float4 t = *(float4*)ptr;
            t.x += w*a.x; t.y += w*a.y; t.z += w*a.z; t.w += w*a.w;
            *(float4*)ptr = t;
          }
        }
        rA = rB; a = b; rB = rC; b = cc; rC = rD;
      }
    }
  }
  __syncthreads();
  int dst = s0 + lrow;
  if (lrow < rows && dst < n) {
    float4* drow = (float4*)(Tbuf + (size_t)lrow * LD);
    const float4* srow = (const float4*)T;
    #pragma unroll 4
    for (int q = tid; q < KTOT/4; q += 128) drow[q] = srow[q];
    const float4* xr = (const float4*)(xin + (size_t)dst * CIN);
    if (tid < CIN/4) drow[KTOT/4 + tid] = xr[tid];
  }
}

// ---------------- split-K blocked GEMM (R12 verbatim, KSPLIT=8) ----------------
template<int CIN, int KSPLIT>
__global__ __launch_bounds__(128) void k_gemm_sk(const float* __restrict__ Tbuf,
                                                 const float* __restrict__ Wc,
                                                 const float* __restrict__ Wd,
                                                 float* __restrict__ P,
                                                 int rows, int n) {
  constexpr int KTOT = 64 * CIN;
  constexpr int LD = KTOT + CIN;
  constexpr int TILES = LD / 32;
  constexpr int TPC = (TILES + KSPLIT - 1) / KSPLIT;
  __shared__ float Al[32][32];
  __shared__ float Bl[32*64];
  int tid = threadIdx.x;
  int tx = tid & 15, ty = tid >> 4;
  int r = tid & 31, kb = (tid >> 5) * 8;
  int m0 = blockIdx.x * 32;
  int chunk = blockIdx.y;
  int cbeg = chunk * TPC * 32;
  int cend = (chunk + 1) * TPC * 32; if (cend > LD) cend = LD;
  const float* Abase = Tbuf + (size_t)m0 * LD + (size_t)r * LD;
  float C[4][4] = {{0}};
  float4 aN0, aN1, bN0, bN1, bN2, bN3;
  auto loadnext = [&](int c0) {
    const float* ap = Abase + c0 + kb;
    aN0 = *(const float4*)ap;
    aN1 = *(const float4*)(ap + 4);
    const float4* bs = (const float4*)((c0 < KTOT) ? (Wc + (size_t)c0 * 64)
                                                   : (Wd + (size_t)(c0 - KTOT) * 64));
    bN0 = bs[tid]; bN1 = bs[tid+128]; bN2 = bs[tid+256]; bN3 = bs[tid+384];
  };
  if (cbeg >= cend) return;
  loadnext(cbeg);
  for (int c0 = cbeg; c0 < cend; c0 += 32) {
    Al[kb+0][r] = aN0.x; Al[kb+1][r] = aN0.y; Al[kb+2][r] = aN0.z; Al[kb+3][r] = aN0.w;
    Al[kb+4][r] = aN1.x; Al[kb+5][r] = aN1.y; Al[kb+6][r] = aN1.z; Al[kb+7][r] = aN1.w;
    float4* bl4 = (float4*)Bl;
    bl4[tid] = bN0; bl4[tid+128] = bN1; bl4[tid+256] = bN2; bl4[tid+384] = bN3;
    __syncthreads();
    if (c0 + 32 < cend) loadnext(c0 + 32);
    #pragma unroll 8
    for (int k = 0; k < 32; ++k) {
      float4 av = *(const float4*)&Al[k][ty*4];
      float4 bv = *(const float4*)&Bl[k*64 + tx*4];
      C[0][0] += av.x*bv.x; C[0][1] += av.x*bv.y; C[0][2] += av.x*bv.z; C[0][3] += av.x*bv.w;
      C[1][0] += av.y*bv.x; C[1][1] += av.y*bv.y; C[1][2] += av.y*bv.z; C[1][3] += av.y*bv.w;
      C[2][0] += av.z*bv.x; C[2][1] += av.z*bv.y; C[2][2] += av.z*bv.z; C[2][3] += av.z*bv.w;
      C[3][0] += av.w*bv.x; C[3][1] += av.w*bv.y; C[3][2] += av.w*bv.z; C[3][3] += av.w*bv.w;
    }
    __syncthreads();
  }
  float* Pc = P + (size_t)chunk * n * 64;
  #pragma unroll
  for (int i = 0; i < 4; ++i) {
    int lrow = m0 + ty*4 + i;
    if (lrow < rows) {
      float4 v; v.x = C[i][0]; v.y = C[i][1]; v.z = C[i][2]; v.w = C[i][3];
      ((float4*)(Pc + (size_t)lrow * 64))[tx] = v;
    }
  }
}

// ---------------- epilogue (R12 verbatim) ----------------
template<int KSPLIT>
__global__ __launch_bounds__(256) void k_epi(const float* __restrict__ P,
                                             const float* __restrict__ bc,
                                             const float* __restrict__ bd,
                                             const float* __restrict__ hres,
                                             float* __restrict__ hout,
                                             float* __restrict__ xout,
                                             int s0, int rows, int n) {
  int idx = blockIdx.x * 256 + threadIdx.x;
  if (idx >= rows * 16) return;
  int lrow = idx >> 4, c4 = idx & 15;
  int dst = s0 + lrow;
  if (dst >= n) return;
  float4 v = ((const float4*)(P + (size_t)lrow * 64))[c4];
  #pragma unroll
  for (int k = 1; k < KSPLIT; ++k) {
    float4 p = ((const float4*)(P + ((size_t)k * n + lrow) * 64))[c4];
    v.x += p.x; v.y += p.y; v.z += p.z; v.w += p.w;
  }
  float4 b1 = ((const float4*)bc)[c4];
  float4 b2 = ((const float4*)bd)[c4];
  v.x += b1.x + b2.x; v.y += b1.y + b2.y; v.z += b1.z + b2.z; v.w += b1.w + b2.w;
  if (hres) {
    float4 h = ((const float4*)hres)[(size_t)dst*16 + c4];
    v.x += h.x; v.y += h.y; v.z += h.z; v.w += h.w;
  }
  if (hout) ((float4*)hout)[(size_t)dst*16 + c4] = v;
  float4 rl;
  rl.x = fmaxf(v.x, 0.f); rl.y = fmaxf(v.y, 0.f);
  rl.z = fmaxf(v.z, 0.f); rl.w = fmaxf(v.w, 0.f);
  ((float4*)xout)[(size_t)dst*16 + c4] = rl;
}

// ---------------- fused layer3 v2: 4 active scatter waves, dual LDS T ----------------
// wave = (edge-half eh, dz-half dzw); T[eh] buffers are disjoint per (eh,dzw,corner).
// Dot (once per block, R12 arithmetic) reads T[0][k]+T[1][k] (half-subtotal regroup,
// same accepted class as KSPLIT). Chain length halves; dot NOT duplicated (fix of R13).
__global__ __launch_bounds__(256) void k_l3fused(const float* __restrict__ xin,
                                                 const int* __restrict__ rowp,
                                                 const ERec* __restrict__ geo,
                                                 const float* __restrict__ Wc, const float* __restrict__ bc,
                                                 const float* __restrict__ Wd, const float* __restrict__ bd,
                                                 const float* __restrict__ pos,
                                                 const float* __restrict__ pos2,
                                                 float* __restrict__ out, int n) {
  __shared__ float T[2][4096];
  __shared__ float red[4][3];
  int tid = threadIdx.x, lane = tid & 63, wave = tid >> 6;
  int dst = xcd_swizzle(blockIdx.x, gridDim.x);
  for (int idx = tid; idx < 2*4096; idx += 256) ((float*)T)[idx] = 0.0f;
  __syncthreads();
  bool valid = dst < n;
  // ---- scatter phase: all 4 waves; wave -> (dzw, eh) ----
  {
    int dzw = wave & 1, eh = wave >> 1;
    int e0 = 0, e1 = 0;
    if (valid) { e0 = rowp[dst]; e1 = rowp[dst+1]; }
    int emid = e0 + ((e1 - e0 + 1) >> 1);
    int eb = eh ? emid : e0;
    int ee = eh ? e1 : emid;
    float* Tg = T[eh];
    int c = lane >> 4, q = lane & 15;
    int dx = c & 1, dy = (c >> 1) & 1;
    int coff = (dzw*16 + dy*4 + dx) * 64 + q*4;
    ERec rA, rB, rC;
    float4 a = make_float4(0,0,0,0), b = a;
    if (eb + 0 < ee) rA = geo[eb + 0];
    if (eb + 1 < ee) rB = geo[eb + 1];
    if (eb + 2 < ee) rC = geo[eb + 2];
    if (eb + 0 < ee) a = *(const float4*)&xin[(size_t)rA.src*64 + q*4];
    if (eb + 1 < ee) b = *(const float4*)&xin[(size_t)rB.src*64 + q*4];
    for (int e = eb; e < ee; ++e) {
      ERec rD;
      if (e + 3 < ee) rD = geo[e + 3];
      float4 cc = make_float4(0,0,0,0);
      if (e + 2 < ee) cc = *(const float4*)&xin[(size_t)rC.src*64 + q*4];
      float w = rA.win * (dzw ? rA.fz : 1.0f - rA.fz)
                       * (dx  ? rA.fx : 1.0f - rA.fx)
                       * (dy  ? rA.fy : 1.0f - rA.fy);
      float* p = &Tg[rA.base*64 + coff];
      float4 t = *(float4*)p;
      t.x += w*a.x; t.y += w*a.y; t.z += w*a.z; t.w += w*a.w;
      *(float4*)p = t;
      rA = rB; a = b; rB = rC; b = cc; rC = rD;
    }
  }
  __syncthreads();
  // ---- dot phase: R12 arithmetic with tv = T0[k]+T1[k] ----
  float a0 = 0, a1 = 0, a2 = 0;
  if (valid) {
    #pragma unroll
    for (int c2 = 0; c2 < 4; ++c2) {
      int k = c2*1024 + tid*4;
      float4 t0 = *(const float4*)&T[0][k];
      float4 t1 = *(const float4*)&T[1][k];
      float4 tv;
      tv.x = t0.x + t1.x; tv.y = t0.y + t1.y; tv.z = t0.z + t1.z; tv.w = t0.w + t1.w;
      float w00 = Wc[(size_t)(k+0)*3+0], w01 = Wc[(size_t)(k+1)*3+0],
            w02 = Wc[(size_t)(k+2)*3+0], w03 = Wc[(size_t)(k+3)*3+0];
      float w10 = Wc[(size_t)(k+0)*3+1], w11 = Wc[(size_t)(k+1)*3+1],
            w12 = Wc[(size_t)(k+2)*3+1], w13 = Wc[(size_t)(k+3)*3+1];
      float w20 = Wc[(size_t)(k+0)*3+2], w21 = Wc[(size_t)(k+1)*3+2],
            w22 = Wc[(size_t)(k+2)*3+2], w23 = Wc[(size_t)(k+3)*3+2];
      a0 += tv.x*w00 + tv.y*w01 + tv.z*w02 + tv.w*w03;
      a1 += tv.x*w10 + tv.y*w11 + tv.z*w12 + tv.w*w13;
      a2 += tv.x*w20 + tv.y*w21 + tv.z*w22 + tv.w*w23;
    }
    if (tid < 16) {
      int k = tid*4;
      float4 tv = *(const float4*)&xin[(size_t)dst*64 + k];
      float w00 = Wd[(k+0)*3+0], w01 = Wd[(k+1)*3+0], w02 = Wd[(k+2)*3+0], w03 = Wd[(k+3)*3+0];
      float w10 = Wd[(k+0)*3+1], w11 = Wd[(k+1)*3+1], w12 = Wd[(k+2)*3+1], w13 = Wd[(k+3)*3+1];
      float w20 = Wd[(k+0)*3+2], w21 = Wd[(k+1)*3+2], w22 = Wd[(k+2)*3+2], w23 = Wd[(k+3)*3+2];
      a0 += tv.x*w00 + tv.y*w01 + tv.z*w02 + tv.w*w03;
      a1 += tv.x*w10 + tv.y*w11 + tv.z*w12 + tv.w*w13;
      a2 += tv.x*w20 + tv.y*w21 + tv.z*w22 + tv.w*w23;
    }
  }
  #pragma unroll
  for (int off = 32; off > 0; off >>= 1) {
    a0 += __shfl_down(a0, off, 64);
    a1 += __shfl_down(a1, off, 64);
    a2 += __shfl_down(a2, off, 64);
  }
  if (lane == 0) { red[wave][0] = a0; red[wave][1] = a1; red[wave][2] = a2; }
  __syncthreads();
  if (tid < 3 && valid) {
    float h3 = red[0][tid] + red[1][tid] + red[2][tid] + red[3][tid] + bc[tid] + bd[tid];
    float pn = pos2[dst*3 + tid] + h3 * (1.0f / 128.0f);
    float vn = (pn - pos[dst*3 + tid]) * (1.0f / DT);
    out[(size_t)dst*6 + tid] = pn;
    out[(size_t)dst*6 + 3 + tid] = vn;
  }
}

// ---------------- host ----------------
extern "C" void kernel_launch(void* const* d_in, const int* in_sizes, int n_in,
                              void* d_out, int out_size, void* d_ws, size_t ws_size,
                              hipStream_t stream) {
  const float* pos    = (const float*)d_in[0];
  const float* vel    = (const float*)d_in[1];
  const float* box    = (const float*)d_in[2];
  const float* bfeats = (const float*)d_in[3];
  const int*   ffsrc  = (const int*)d_in[4];
  const int*   ffdst  = (const int*)d_in[5];
  const int*   bfsrc  = (const int*)d_in[6];
  const int*   bfdst  = (const int*)d_in[7];
  const float* W0f = (const float*)d_in[8];
  const float* b0f = (const float*)d_in[9];
  const float* W0o = (const float*)d_in[10];
  const float* b0o = (const float*)d_in[11];
  const float* Wd0 = (const float*)d_in[12];
  const float* bd0 = (const float*)d_in[13];
  const float* Wc1 = (const float*)d_in[14];
  const float* bc1 = (const float*)d_in[15];
  const float* Wd1 = (const float*)d_in[16];
  const float* bd1 = (const float*)d_in[17];
  const float* Wc2 = (const float*)d_in[18];
  const float* bc2 = (const float*)d_in[19];
  const float* Wd2 = (const float*)d_in[20];
  const float* bd2 = (const float*)d_in[21];
  const float* Wc3 = (const float*)d_in[22];
  const float* bc3 = (const float*)d_in[23];
  const float* Wd3 = (const float*)d_in[24];
  const float* bd3 = (const float*)d_in[25];

  int n   = in_sizes[0] / 3;
  int Eff = in_sizes[4];
  int Ebf = in_sizes[6];
  float* out = (float*)d_out;

  constexpr int KSPLIT = 8;

  char* w = (char*)d_ws;
  size_t used = 0;
  auto alloc = [&](size_t bytes) -> char* {
    char* p = w + used; used += (bytes + 255) & ~size_t(255); return p;
  };
  float* pos2  = (float*)alloc((size_t)n*3*4);
  float* feats = (float*)alloc((size_t)n*4*4);
  float* x0    = (float*)alloc((size_t)n*96*4);
  float* h1    = (float*)alloc((size_t)n*64*4);
  float* x1    = (float*)alloc((size_t)n*64*4);
  float* x2    = (float*)alloc((size_t)n*64*4);
  int*   rowff = (int*)alloc((size_t)(n+1)*4);
  int*   rowbf = (int*)alloc((size_t)(n+1)*4);
  ERec*  gff   = (ERec*)alloc((size_t)Eff*sizeof(ERec));
  ERec*  gbf   = (ERec*)alloc((size_t)Ebf*sizeof(ERec));
  float* Pbuf  = (float*)alloc((size_t)KSPLIT*n*64*4);
  float* Tbuf  = (float*)(w + used);
  size_t rem   = (ws_size > used) ? (ws_size - used) : 0;

  constexpr int LD1 = 64*96 + 96;   // 6240
  constexpr int LD2 = 64*64 + 64;   // 4160
  auto cap_rows = [&](int ld) -> int {
    size_t cr = rem / ((size_t)ld * 4);
    if (cr > (size_t)n) cr = n;
    int c = (int)cr & ~63;
    if (c < 64) c = 64;
    return c;
  };
  int cap1 = cap_rows(LD1);
  int cap2 = cap_rows(LD2);

  k_prep<<<(n+255)/256, 256, 0, stream>>>(pos, vel, pos2, feats, n);
  k_rowptr<<<(n+256)/256, 256, 0, stream>>>(ffdst, Eff, bfdst, Ebf, rowff, rowbf, n);
  k_geom<<<(Eff+255)/256, 256, 0, stream>>>(ffsrc, ffdst, pos2, pos2, gff, Eff);
  k_geom<<<(Ebf+255)/256, 256, 0, stream>>>(bfsrc, bfdst, box,  pos2, gbf, Ebf);
  k_layer0<<<(n+3)/4, 256, 0, stream>>>(feats, bfeats, rowff, gff, rowbf, gbf,
                                        W0f, b0f, W0o, b0o, Wd0, bd0, x0, n);
  // layer1: CIN=96
  for (int s = 0; s < n; s += cap1) {
    int rows = (n - s < cap1) ? (n - s) : cap1;
    k_scatter<96><<<rows, 128, 0, stream>>>(x0, rowff, gff, Tbuf, s, rows, n);
    k_gemm_sk<96,KSPLIT><<<dim3((rows+31)/32, KSPLIT), 128, 0, stream>>>(
        Tbuf, Wc1, Wd1, Pbuf, rows, n);
    k_epi<KSPLIT><<<(rows*16+255)/256, 256, 0, stream>>>(
        Pbuf, bc1, bd1, nullptr, h1, x1, s, rows, n);
  }
  // layer2: CIN=64, residual h1
  for (int s = 0; s < n; s += cap2) {
    int rows = (n - s < cap2) ? (n - s) : cap2;
    k_scatter<64><<<rows, 128, 0, stream>>>(x1, rowff, gff, Tbuf, s, rows, n);
    k_gemm_sk<64,KSPLIT><<<dim3((rows+31)/32, KSPLIT), 128, 0, stream>>>(
        Tbuf, Wc2, Wd2, Pbuf, rows, n);
    k_epi<KSPLIT><<<(rows*16+255)/256, 256, 0, stream>>>(
        Pbuf, bc2, bd2, h1, nullptr, x2, s, rows, n);
  }
  // layer3: fused scatter (4 waves, dual-T) + dot + integrate
  k_l3fused<<<n, 256, 0, stream>>>(x2, rowff, gff, Wc3, bc3, Wd3, bd3,
                                   pos, pos2, out, n);
}

// Round 15
// 1121.816 us; speedup vs baseline: 1.0379x; 1.0376x over previous
//
#include <hip/hip_runtime.h>
#include <math.h>

// ---------------- constants ----------------
constexpr float RADIUS     = 0.1125f;
constexpr float INV_RADIUS = 1.0f / RADIUS;
constexpr float DT         = 1.0f / 50.0f;
constexpr float FOPI       = 1.2732395447351628f; // 4/pi

// packed per-edge record: 32 B, two float4 loads
struct __align__(16) ERec {
  float fx, fy, fz, win;
  int   base, src, pad0, pad1;
};

// XCD-aware block->row swizzle (8 XCDs, round-robin dispatch): give each XCD a
// contiguous dst range so neighboring dsts (sharing ~90% of src rows) share L2.
__device__ __forceinline__ int xcd_swizzle(int b, int nb) {
  return (nb & 7) ? b : ((b & 7) * (nb >> 3) + (b >> 3));
}

// ---------------- prep: pos2, feats=[1,vel2] ----------------
__global__ __launch_bounds__(256) void k_prep(const float* __restrict__ pos,
                                              const float* __restrict__ vel,
                                              float* __restrict__ pos2,
                                              float* __restrict__ feats, int n) {
  int i = blockIdx.x * blockDim.x + threadIdx.x;
  if (i >= n) return;
  float vx = vel[i*3+0], vy = vel[i*3+1], vz = vel[i*3+2];
  float v2x = vx, v2y = vy + DT * (-9.81f), v2z = vz;
  pos2[i*3+0] = pos[i*3+0] + DT * 0.5f * (v2x + vx);
  pos2[i*3+1] = pos[i*3+1] + DT * 0.5f * (v2y + vy);
  pos2[i*3+2] = pos[i*3+2] + DT * 0.5f * (v2z + vz);
  feats[i*4+0] = 1.0f;
  feats[i*4+1] = v2x; feats[i*4+2] = v2y; feats[i*4+3] = v2z;
}

// ---------------- rowptr ----------------
__global__ __launch_bounds__(256) void k_rowptr(const int* __restrict__ ffdst, int Eff,
                                                const int* __restrict__ bfdst, int Ebf,
                                                int* __restrict__ rowff, int* __restrict__ rowbf,
                                                int n) {
  int d = blockIdx.x * blockDim.x + threadIdx.x;
  if (d > n) return;
  { int lo = 0, hi = Eff;
    while (lo < hi) { int mid = (lo + hi) >> 1; if (ffdst[mid] < d) lo = mid + 1; else hi = mid; }
    rowff[d] = lo; }
  { int lo = 0, hi = Ebf;
    while (lo < hi) { int mid = (lo + hi) >> 1; if (bfdst[mid] < d) lo = mid + 1; else hi = mid; }
    rowbf[d] = lo; }
}

// ---------------- per-edge geometry -> packed ERec ----------------
__global__ __launch_bounds__(256) void k_geom(const int* __restrict__ srcs,
                                              const int* __restrict__ dsts,
                                              const float* __restrict__ srcpos,
                                              const float* __restrict__ dstpos,
                                              ERec* __restrict__ geo, int E) {
  int e = blockIdx.x * blockDim.x + threadIdx.x;
  if (e >= E) return;
  int s = srcs[e], d = dsts[e];
  float rx = (srcpos[s*3+0] - dstpos[d*3+0]) * INV_RADIUS;
  float ry = (srcpos[s*3+1] - dstpos[d*3+1]) * INV_RADIUS;
  float rz = (srcpos[s*3+2] - dstpos[d*3+2]) * INV_RADIUS;
  float r2 = rx*rx + ry*ry + rz*rz;
  float t = 1.0f - r2;
  float win = t * t * t;
  win = fminf(fmaxf(win, 0.0f), 1.0f);
  float x = rx, y = ry, z = rz;
  float sq = r2;
  float norm = sqrtf(sq + 1e-24f);
  float xy_sq = x*x + y*y;
  bool zero = sq < 1e-12f;
  bool cone = 1.25f * z * z > xy_sq;
  float s_cone = sqrtf(3.0f * norm / (norm + fabsf(z) + 1e-12f));
  float s_side = norm / sqrtf(xy_sq + 1e-24f);
  float sgnz = (z > 0.0f) ? 1.0f : ((z < 0.0f) ? -1.0f : 0.0f);
  float xc = zero ? 0.0f : (cone ? x * s_cone : x * s_side);
  float yc = zero ? 0.0f : (cone ? y * s_cone : y * s_side);
  float zc = zero ? 0.0f : (cone ? sgnz * norm : 1.5f * z);
  float nxy_sq = xc*xc + yc*yc;
  float nxy = sqrtf(nxy_sq + 1e-24f);
  bool zero_xy = nxy_sq < 1e-12f;
  bool xbig = fabsf(xc) > fabsf(yc);
  float dx_ = (fabsf(xc) > 1e-12f) ? xc : 1.0f;
  float dy_ = (fabsf(yc) > 1e-12f) ? yc : 1.0f;
  float sgnx = (xc > 0.0f) ? 1.0f : ((xc < 0.0f) ? -1.0f : 0.0f);
  float sgny = (yc > 0.0f) ? 1.0f : ((yc < 0.0f) ? -1.0f : 0.0f);
  float tx = sgnx * nxy, ty = sgny * nxy;
  float xq = zero_xy ? 0.0f : (xbig ? tx : ty * FOPI * atanf(xc / dy_));
  float yq = zero_xy ? 0.0f : (xbig ? tx * FOPI * atanf(yc / dx_) : ty);
  float gx = (xq + 1.0f) * 1.5f;
  float gy = (yq + 1.0f) * 1.5f;
  float gz = (zc + 1.0f) * 1.5f;
  float g0x = fminf(fmaxf(floorf(gx), 0.0f), 2.0f);
  float g0y = fminf(fmaxf(floorf(gy), 0.0f), 2.0f);
  float g0z = fminf(fmaxf(floorf(gz), 0.0f), 2.0f);
  ERec g;
  g.fx = gx - g0x; g.fy = gy - g0y; g.fz = gz - g0z; g.win = win;
  g.base = (int)g0z * 16 + (int)g0y * 4 + (int)g0x;
  g.src = s; g.pad0 = 0; g.pad1 = 0;
  geo[e] = g;
}

// ---------------- layer0: lane=bin register-gather ----------------
__global__ __launch_bounds__(256) void k_layer0(const float* __restrict__ feats,
                                                const float* __restrict__ bfeats,
                                                const int* __restrict__ rowff,
                                                const ERec* __restrict__ gff,
                                                const int* __restrict__ rowbf,
                                                const ERec* __restrict__ gbf,
                                                const float* __restrict__ W0f, const float* __restrict__ b0f,
                                                const float* __restrict__ W0o, const float* __restrict__ b0o,
                                                const float* __restrict__ Wd0, const float* __restrict__ bd0,
                                                float* __restrict__ x0, int n) {
  __shared__ float Tf[4][256];   // [dst][bin*4+ch]
  __shared__ float To[4][256];   // [dst][bin*4+ch] (ch<3 used)
  int tid = threadIdx.x, lane = tid & 63, g = tid >> 6;
  int bsw = xcd_swizzle(blockIdx.x, gridDim.x);
  int dst = bsw * 4 + g;
  bool valid = dst < n;
  int bx = lane & 3, by = (lane >> 2) & 3, bz = lane >> 4;
  float a0 = 0, a1 = 0, a2 = 0, a3 = 0;   // ff accumulators (4 ch)
  float q0 = 0, q1 = 0, q2 = 0;           // bf accumulators (3 ch)
  // ---- ff edges (depth-2 prefetch) ----
  {
    int e0 = valid ? rowff[dst] : 0, e1 = valid ? rowff[dst+1] : 0;
    ERec rA, rB; float4 fA = make_float4(0,0,0,0), fB = fA;
    if (e0 + 0 < e1) { rA = gff[e0 + 0]; fA = *(const float4*)&feats[(size_t)rA.src*4]; }
    if (e0 + 1 < e1) { rB = gff[e0 + 1]; fB = *(const float4*)&feats[(size_t)rB.src*4]; }
    for (int e = e0; e < e1; ++e) {
      ERec rC; float4 fC = make_float4(0,0,0,0);
      if (e + 2 < e1) { rC = gff[e + 2]; fC = *(const float4*)&feats[(size_t)rC.src*4]; }
      int gx = rA.base & 3, gy = (rA.base >> 2) & 3, gz = rA.base >> 4;
      float wx = (bx == gx) ? (1.0f - rA.fx) : ((bx == gx + 1) ? rA.fx : 0.0f);
      float wy = (by == gy) ? (1.0f - rA.fy) : ((by == gy + 1) ? rA.fy : 0.0f);
      float wz = (bz == gz) ? (1.0f - rA.fz) : ((bz == gz + 1) ? rA.fz : 0.0f);
      float w = rA.win * wx * wy * wz;
      a0 += w * fA.x; a1 += w * fA.y; a2 += w * fA.z; a3 += w * fA.w;
      rA = rB; fA = fB; rB = rC; fB = fC;
    }
  }
  // ---- bf edges ----
  {
    int e0 = valid ? rowbf[dst] : 0, e1 = valid ? rowbf[dst+1] : 0;
    ERec rA, rB; float fA0=0,fA1=0,fA2=0, fB0=0,fB1=0,fB2=0;
    if (e0 + 0 < e1) { rA = gbf[e0 + 0]; const float* p=&bfeats[(size_t)rA.src*3]; fA0=p[0]; fA1=p[1]; fA2=p[2]; }
    if (e0 + 1 < e1) { rB = gbf[e0 + 1]; const float* p=&bfeats[(size_t)rB.src*3]; fB0=p[0]; fB1=p[1]; fB2=p[2]; }
    for (int e = e0; e < e1; ++e) {
      ERec rC; float fC0=0,fC1=0,fC2=0;
      if (e + 2 < e1) { rC = gbf[e + 2]; const float* p=&bfeats[(size_t)rC.src*3]; fC0=p[0]; fC1=p[1]; fC2=p[2]; }
      int gx = rA.base & 3, gy = (rA.base >> 2) & 3, gz = rA.base >> 4;
      float wx = (bx == gx) ? (1.0f - rA.fx) : ((bx == gx + 1) ? rA.fx : 0.0f);
      float wy = (by == gy) ? (1.0f - rA.fy) : ((by == gy + 1) ? rA.fy : 0.0f);
      float wz = (bz == gz) ? (1.0f - rA.fz) : ((bz == gz + 1) ? rA.fz : 0.0f);
      float w = rA.win * wx * wy * wz;
      q0 += w * fA0; q1 += w * fA1; q2 += w * fA2;
      rA = rB; fA0 = fB0; fA1 = fB1; fA2 = fB2;
      rB = rC; fB0 = fC0; fB1 = fC1; fB2 = fC2;
    }
  }
  // park register T into LDS (one b128 each)
  *(float4*)&Tf[g][lane*4] = make_float4(a0, a1, a2, a3);
  *(float4*)&To[g][lane*4] = make_float4(q0, q1, q2, 0.0f);
  __syncthreads();
  // ---- GEMM: o = lane&31, halves over bins, broadcast LDS reads ----
  int o = lane & 31, h = lane >> 5;
  float accF = 0.0f, accO = 0.0f;
  const float* Tfg = Tf[g];
  const float* Tog = To[g];
  #pragma unroll 4
  for (int bin = h*32; bin < h*32 + 32; ++bin) {
    float4 t = *(const float4*)&Tfg[bin*4];
    const float* wf = W0f + bin*128 + o;
    accF += t.x*wf[0] + t.y*wf[32] + t.z*wf[64] + t.w*wf[96];
    float4 u = *(const float4*)&Tog[bin*4];
    const float* wo = W0o + bin*96 + o;
    accO += u.x*wo[0] + u.y*wo[32] + u.z*wo[64];
  }
  accF += __shfl_down(accF, 32, 64);
  accO += __shfl_down(accO, 32, 64);
  if (lane < 32 && valid) {
    float4 fdv = *(const float4*)&feats[(size_t)dst*4];
    float d0 = bd0[o] + fdv.x*Wd0[o] + fdv.y*Wd0[32+o] + fdv.z*Wd0[64+o] + fdv.w*Wd0[96+o];
    x0[(size_t)dst*96 + o]      = fmaxf(accO + b0o[o], 0.0f);
    x0[(size_t)dst*96 + 32 + o] = fmaxf(accF + b0f[o], 0.0f);
    x0[(size_t)dst*96 + 64 + o] = fmaxf(d0, 0.0f);
  }
}

// ---------------- scatter: T rows [T(64*CIN) | xin(CIN)] -> HBM ----------------
// 1 dst/block, 128 threads (2 waves split by dz). Vectorized LDS RMW (no atomics).
template<int CIN>
__global__ __launch_bounds__(128) void k_scatter(const float* __restrict__ xin,
                                                 const int* __restrict__ rowp,
                                                 const ERec* __restrict__ geo,
                                                 float* __restrict__ Tbuf,
                                                 int s0, int rows, int n) {
  constexpr int KTOT = 64 * CIN;
  constexpr int LD = KTOT + CIN;
  __shared__ float T[KTOT];
  int tid = threadIdx.x;
  for (int idx = tid; idx < KTOT; idx += 128) T[idx] = 0.0f;
  __syncthreads();
  int lrow = xcd_swizzle(blockIdx.x, gridDim.x);
  {
    int dzw = tid >> 6, lane = tid & 63;
    int dst = s0 + lrow;
    int e0 = 0, e1 = 0;
    if (lrow < rows && dst < n) { e0 = rowp[dst]; e1 = rowp[dst+1]; }
    if constexpr (CIN == 64) {
      int c = lane >> 4, q = lane & 15;
      int dx = c & 1, dy = (c >> 1) & 1;
      int coff = (dzw*16 + dy*4 + dx) * 64 + q*4;
      ERec rA, rB, rC;
      float4 a = make_float4(0,0,0,0), b = a;
      if (e0 + 0 < e1) rA = geo[e0 + 0];
      if (e0 + 1 < e1) rB = geo[e0 + 1];
      if (e0 + 2 < e1) rC = geo[e0 + 2];
      if (e0 + 0 < e1) a = *(const float4*)&xin[(size_t)rA.src*64 + q*4];
      if (e0 + 1 < e1) b = *(const float4*)&xin[(size_t)rB.src*64 + q*4];
      for (int e = e0; e < e1; ++e) {
        ERec rD;
        if (e + 3 < e1) rD = geo[e + 3];
        float4 cc = make_float4(0,0,0,0);
        if (e + 2 < e1) cc = *(const float4*)&xin[(size_t)rC.src*64 + q*4];
        float w = rA.win * (dzw ? rA.fz : 1.0f - rA.fz)
                         * (dx  ? rA.fx : 1.0f - rA.fx)
                         * (dy  ? rA.fy : 1.0f - rA.fy);
        float* p = &T[rA.base*64 + coff];
        float4 t = *(float4*)p;
        t.x += w*a.x; t.y += w*a.y; t.z += w*a.z; t.w += w*a.w;
        *(float4*)p = t;
        rA = rB; a = b; rB = rC; b = cc; rC = rD;
      }
    } else {
      // CIN == 96: lanes 0..47 active; pass p covers corners {2p, 2p+1};
      // lane: corner-sub cq = lane/24, channel quad q = lane%24 (float4).
      bool act = lane < 48;
      int cq = lane / 24;
      int q  = lane - 24*cq;
      ERec rA, rB, rC;
      float4 a = make_float4(0,0,0,0), b = a;
      if (e0 + 0 < e1) rA = geo[e0 + 0];
      if (e0 + 1 < e1) rB = geo[e0 + 1];
      if (e0 + 2 < e1) rC = geo[e0 + 2];
      if (e0 + 0 < e1 && act) a = *(const float4*)&xin[(size_t)rA.src*96 + q*4];
      if (e0 + 1 < e1 && act) b = *(const float4*)&xin[(size_t)rB.src*96 + q*4];
      for (int e = e0; e < e1; ++e) {
        ERec rD;
        if (e + 3 < e1) rD = geo[e + 3];
        float4 cc = make_float4(0,0,0,0);
        if (e + 2 < e1 && act) cc = *(const float4*)&xin[(size_t)rC.src*96 + q*4];
        if (act) {
          float wz = rA.win * (dzw ? rA.fz : 1.0f - rA.fz);
          float wx0 = 1.0f - rA.fx, wx1 = rA.fx;
          float wy0 = 1.0f - rA.fy, wy1 = rA.fy;
          int tb = (rA.base + dzw*16)*96 + q*4;
          #pragma unroll
          for (int p = 0; p < 2; ++p) {
            int c = p*2 + cq;
            int dx = c & 1, dy = c >> 1;
            float w = wz * (dx ? wx1 : wx0) * (dy ? wy1 : wy0);
            float* ptr = &T[tb + (dy*4 + dx)*96];
            float4 t = *(float4*)ptr;
            t.x += w*a.x; t.y += w*a.y; t.z += w*a.z; t.w += w*a.w;
            *(float4*)ptr = t;
          }
        }
        rA = rB; a = b; rB = rC; b = cc; rC = rD;
      }
    }
  }
  __syncthreads();
  int dst = s0 + lrow;
  if (lrow < rows && dst < n) {
    float4* drow = (float4*)(Tbuf + (size_t)lrow * LD);
    const float4* srow = (const float4*)T;
    #pragma unroll 4
    for (int q = tid; q < KTOT/4; q += 128) drow[q] = srow[q];
    const float4* xr = (const float4*)(xin + (size_t)dst * CIN);
    if (tid < CIN/4) drow[KTOT/4 + tid] = xr[tid];
  }
}

// ---------------- split-K blocked GEMM (KSPLIT=8) ----------------
template<int CIN, int KSPLIT>
__global__ __launch_bounds__(128) void k_gemm_sk(const float* __restrict__ Tbuf,
                                                 const float* __restrict__ Wc,
                                                 const float* __restrict__ Wd,
                                                 float* __restrict__ P,
                                                 int rows, int n) {
  constexpr int KTOT = 64 * CIN;
  constexpr int LD = KTOT + CIN;
  constexpr int TILES = LD / 32;
  constexpr int TPC = (TILES + KSPLIT - 1) / KSPLIT;
  __shared__ float Al[32][32];
  __shared__ float Bl[32*64];
  int tid = threadIdx.x;
  int tx = tid & 15, ty = tid >> 4;
  int r = tid & 31, kb = (tid >> 5) * 8;
  int m0 = blockIdx.x * 32;
  int chunk = blockIdx.y;
  int cbeg = chunk * TPC * 32;
  int cend = (chunk + 1) * TPC * 32; if (cend > LD) cend = LD;
  const float* Abase = Tbuf + (size_t)m0 * LD + (size_t)r * LD;
  float C[4][4] = {{0}};
  float4 aN0, aN1, bN0, bN1, bN2, bN3;
  auto loadnext = [&](int c0) {
    const float* ap = Abase + c0 + kb;
    aN0 = *(const float4*)ap;
    aN1 = *(const float4*)(ap + 4);
    const float4* bs = (const float4*)((c0 < KTOT) ? (Wc + (size_t)c0 * 64)
                                                   : (Wd + (size_t)(c0 - KTOT) * 64));
    bN0 = bs[tid]; bN1 = bs[tid+128]; bN2 = bs[tid+256]; bN3 = bs[tid+384];
  };
  if (cbeg >= cend) return;
  loadnext(cbeg);
  for (int c0 = cbeg; c0 < cend; c0 += 32) {
    Al[kb+0][r] = aN0.x; Al[kb+1][r] = aN0.y; Al[kb+2][r] = aN0.z; Al[kb+3][r] = aN0.w;
    Al[kb+4][r] = aN1.x; Al[kb+5][r] = aN1.y; Al[kb+6][r] = aN1.z; Al[kb+7][r] = aN1.w;
    float4* bl4 = (float4*)Bl;
    bl4[tid] = bN0; bl4[tid+128] = bN1; bl4[tid+256] = bN2; bl4[tid+384] = bN3;
    __syncthreads();
    if (c0 + 32 < cend) loadnext(c0 + 32);
    #pragma unroll 8
    for (int k = 0; k < 32; ++k) {
      float4 av = *(const float4*)&Al[k][ty*4];
      float4 bv = *(const float4*)&Bl[k*64 + tx*4];
      C[0][0] += av.x*bv.x; C[0][1] += av.x*bv.y; C[0][2] += av.x*bv.z; C[0][3] += av.x*bv.w;
      C[1][0] += av.y*bv.x; C[1][1] += av.y*bv.y; C[1][2] += av.y*bv.z; C[1][3] += av.y*bv.w;
      C[2][0] += av.z*bv.x; C[2][1] += av.z*bv.y; C[2][2] += av.z*bv.z; C[2][3] += av.z*bv.w;
      C[3][0] += av.w*bv.x; C[3][1] += av.w*bv.y; C[3][2] += av.w*bv.z; C[3][3] += av.w*bv.w;
    }
    __syncthreads();
  }
  float* Pc = P + (size_t)chunk * n * 64;
  #pragma unroll
  for (int i = 0; i < 4; ++i) {
    int lrow = m0 + ty*4 + i;
    if (lrow < rows) {
      float4 v; v.x = C[i][0]; v.y = C[i][1]; v.z = C[i][2]; v.w = C[i][3];
      ((float4*)(Pc + (size_t)lrow * 64))[tx] = v;
    }
  }
}

// ---------------- epilogue ----------------
template<int KSPLIT>
__global__ __launch_bounds__(256) void k_epi(const float* __restrict__ P,
                                             const float* __restrict__ bc,
                                             const float* __restrict__ bd,
                                             const float* __restrict__ hres,
                                             float* __restrict__ hout,
                                             float* __restrict__ xout,
                                             int s0, int rows, int n) {
  int idx = blockIdx.x * 256 + threadIdx.x;
  if (idx >= rows * 16) return;
  int lrow = idx >> 4, c4 = idx & 15;
  int dst = s0 + lrow;
  if (dst >= n) return;
  float4 v = ((const float4*)(P + (size_t)lrow * 64))[c4];
  #pragma unroll
  for (int k = 1; k < KSPLIT; ++k) {
    float4 p = ((const float4*)(P + ((size_t)k * n + lrow) * 64))[c4];
    v.x += p.x; v.y += p.y; v.z += p.z; v.w += p.w;
  }
  float4 b1 = ((const float4*)bc)[c4];
  float4 b2 = ((const float4*)bd)[c4];
  v.x += b1.x + b2.x; v.y += b1.y + b2.y; v.z += b1.z + b2.z; v.w += b1.w + b2.w;
  if (hres) {
    float4 h = ((const float4*)hres)[(size_t)dst*16 + c4];
    v.x += h.x; v.y += h.y; v.z += h.z; v.w += h.w;
  }
  if (hout) ((float4*)hout)[(size_t)dst*16 + c4] = v;
  float4 rl;
  rl.x = fmaxf(v.x, 0.f); rl.y = fmaxf(v.y, 0.f);
  rl.z = fmaxf(v.z, 0.f); rl.w = fmaxf(v.w, 0.f);
  ((float4*)xout)[(size_t)dst*16 + c4] = rl;
}

// ---------------- fused layer3: single-T scatter + exact out3 dot + integrate ----------------
__global__ __launch_bounds__(256) void k_l3fused(const float* __restrict__ xin,
                                                 const int* __restrict__ rowp,
                                                 const ERec* __restrict__ geo,
                                                 const float* __restrict__ Wc, const float* __restrict__ bc,
                                                 const float* __restrict__ Wd, const float* __restrict__ bd,
                                                 const float* __restrict__ pos,
                                                 const float* __restrict__ pos2,
                                                 float* __restrict__ out, int n) {
  __shared__ float T[4096];
  __shared__ float red[4][3];
  int tid = threadIdx.x, lane = tid & 63, wave = tid >> 6;
  int dst = xcd_swizzle(blockIdx.x, gridDim.x);
  for (int idx = tid; idx < 4096; idx += 256) T[idx] = 0.0f;
  __syncthreads();
  // ---- scatter phase: exact R9 body, active on tid<128 ----
  if (tid < 128) {
    int dzw = tid >> 6, lane2 = tid & 63;
    int e0 = 0, e1 = 0;
    if (dst < n) { e0 = rowp[dst]; e1 = rowp[dst+1]; }
    int c = lane2 >> 4, q = lane2 & 15;
    int dx = c & 1, dy = (c >> 1) & 1;
    int coff = (dzw*16 + dy*4 + dx) * 64 + q*4;
    ERec rA, rB, rC;
    float4 a = make_float4(0,0,0,0), b = a;
    if (e0 + 0 < e1) rA = geo[e0 + 0];
    if (e0 + 1 < e1) rB = geo[e0 + 1];
    if (e0 + 2 < e1) rC = geo[e0 + 2];
    if (e0 + 0 < e1) a = *(const float4*)&xin[(size_t)rA.src*64 + q*4];
    if (e0 + 1 < e1) b = *(const float4*)&xin[(size_t)rB.src*64 + q*4];
    for (int e = e0; e < e1; ++e) {
      ERec rD;
      if (e + 3 < e1) rD = geo[e + 3];
      float4 cc = make_float4(0,0,0,0);
      if (e + 2 < e1) cc = *(const float4*)&xin[(size_t)rC.src*64 + q*4];
      float w = rA.win * (dzw ? rA.fz : 1.0f - rA.fz)
                       * (dx  ? rA.fx : 1.0f - rA.fx)
                       * (dy  ? rA.fy : 1.0f - rA.fy);
      float* p = &T[rA.base*64 + coff];
      float4 t = *(float4*)p;
      t.x += w*a.x; t.y += w*a.y; t.z += w*a.z; t.w += w*a.w;
      *(float4*)p = t;
      rA = rB; a = b; rB = rC; b = cc; rC = rD;
    }
  }
  __syncthreads();
  // ---- dot phase: exact k_out3 arithmetic ----
  bool valid = dst < n;
  float a0 = 0, a1 = 0, a2 = 0;
  if (valid) {
    #pragma unroll
    for (int c2 = 0; c2 < 4; ++c2) {
      int k = c2*1024 + tid*4;
      float4 tv = *(const float4*)&T[k];
      float w00 = Wc[(size_t)(k+0)*3+0], w01 = Wc[(size_t)(k+1)*3+0],
            w02 = Wc[(size_t)(k+2)*3+0], w03 = Wc[(size_t)(k+3)*3+0];
      float w10 = Wc[(size_t)(k+0)*3+1], w11 = Wc[(size_t)(k+1)*3+1],
            w12 = Wc[(size_t)(k+2)*3+1], w13 = Wc[(size_t)(k+3)*3+1];
      float w20 = Wc[(size_t)(k+0)*3+2], w21 = Wc[(size_t)(k+1)*3+2],
            w22 = Wc[(size_t)(k+2)*3+2], w23 = Wc[(size_t)(k+3)*3+2];
      a0 += tv.x*w00 + tv.y*w01 + tv.z*w02 + tv.w*w03;
      a1 += tv.x*w10 + tv.y*w11 + tv.z*w12 + tv.w*w13;
      a2 += tv.x*w20 + tv.y*w21 + tv.z*w22 + tv.w*w23;
    }
    if (tid < 16) {
      int k = tid*4;
      float4 tv = *(const float4*)&xin[(size_t)dst*64 + k];
      float w00 = Wd[(k+0)*3+0], w01 = Wd[(k+1)*3+0], w02 = Wd[(k+2)*3+0], w03 = Wd[(k+3)*3+0];
      float w10 = Wd[(k+0)*3+1], w11 = Wd[(k+1)*3+1], w12 = Wd[(k+2)*3+1], w13 = Wd[(k+3)*3+1];
      float w20 = Wd[(k+0)*3+2], w21 = Wd[(k+1)*3+2], w22 = Wd[(k+2)*3+2], w23 = Wd[(k+3)*3+2];
      a0 += tv.x*w00 + tv.y*w01 + tv.z*w02 + tv.w*w03;
      a1 += tv.x*w10 + tv.y*w11 + tv.z*w12 + tv.w*w13;
      a2 += tv.x*w20 + tv.y*w21 + tv.z*w22 + tv.w*w23;
    }
  }
  #pragma unroll
  for (int off = 32; off > 0; off >>= 1) {
    a0 += __shfl_down(a0, off, 64);
    a1 += __shfl_down(a1, off, 64);
    a2 += __shfl_down(a2, off, 64);
  }
  if (lane == 0) { red[wave][0] = a0; red[wave][1] = a1; red[wave][2] = a2; }
  __syncthreads();
  if (tid < 3 && valid) {
    float h3 = red[0][tid] + red[1][tid] + red[2][tid] + red[3][tid] + bc[tid] + bd[tid];
    float pn = pos2[dst*3 + tid] + h3 * (1.0f / 128.0f);
    float vn = (pn - pos[dst*3 + tid]) * (1.0f / DT);
    out[(size_t)dst*6 + tid] = pn;
    out[(size_t)dst*6 + 3 + tid] = vn;
  }
}

// ---------------- host ----------------
extern "C" void kernel_launch(void* const* d_in, const int* in_sizes, int n_in,
                              void* d_out, int out_size, void* d_ws, size_t ws_size,
                              hipStream_t stream) {
  const float* pos    = (const float*)d_in[0];
  const float* vel    = (const float*)d_in[1];
  const float* box    = (const float*)d_in[2];
  const float* bfeats = (const float*)d_in[3];
  const int*   ffsrc  = (const int*)d_in[4];
  const int*   ffdst  = (const int*)d_in[5];
  const int*   bfsrc  = (const int*)d_in[6];
  const int*   bfdst  = (const int*)d_in[7];
  const float* W0f = (const float*)d_in[8];
  const float* b0f = (const float*)d_in[9];
  const float* W0o = (const float*)d_in[10];
  const float* b0o = (const float*)d_in[11];
  const float* Wd0 = (const float*)d_in[12];
  const float* bd0 = (const float*)d_in[13];
  const float* Wc1 = (const float*)d_in[14];
  const float* bc1 = (const float*)d_in[15];
  const float* Wd1 = (const float*)d_in[16];
  const float* bd1 = (const float*)d_in[17];
  const float* Wc2 = (const float*)d_in[18];
  const float* bc2 = (const float*)d_in[19];
  const float* Wd2 = (const float*)d_in[20];
  const float* bd2 = (const float*)d_in[21];
  const float* Wc3 = (const float*)d_in[22];
  const float* bc3 = (const float*)d_in[23];
  const float* Wd3 = (const float*)d_in[24];
  const float* bd3 = (const float*)d_in[25];

  int n   = in_sizes[0] / 3;
  int Eff = in_sizes[4];
  int Ebf = in_sizes[6];
  float* out = (float*)d_out;

  constexpr int KSPLIT = 8;

  char* w = (char*)d_ws;
  size_t used = 0;
  auto alloc = [&](size_t bytes) -> char* {
    char* p = w + used; used += (bytes + 255) & ~size_t(255); return p;
  };
  float* pos2  = (float*)alloc((size_t)n*3*4);
  float* feats = (float*)alloc((size_t)n*4*4);
  float* x0    = (float*)alloc((size_t)n*96*4);
  float* h1    = (float*)alloc((size_t)n*64*4);
  float* x1    = (float*)alloc((size_t)n*64*4);
  float* x2    = (float*)alloc((size_t)n*64*4);
  int*   rowff = (int*)alloc((size_t)(n+1)*4);
  int*   rowbf = (int*)alloc((size_t)(n+1)*4);
  ERec*  gff   = (ERec*)alloc((size_t)Eff*sizeof(ERec));
  ERec*  gbf   = (ERec*)alloc((size_t)Ebf*sizeof(ERec));
  float* Pbuf  = (float*)alloc((size_t)KSPLIT*n*64*4);
  float* Tbuf  = (float*)(w + used);
  size_t rem   = (ws_size > used) ? (ws_size - used) : 0;

  constexpr int LD1 = 64*96 + 96;   // 6240
  constexpr int LD2 = 64*64 + 64;   // 4160
  auto cap_rows = [&](int ld) -> int {
    size_t cr = rem / ((size_t)ld * 4);
    if (cr > (size_t)n) cr = n;
    int c = (int)cr & ~63;
    if (c < 64) c = 64;
    return c;
  };
  int cap1 = cap_rows(LD1);
  int cap2 = cap_rows(LD2);

  k_prep<<<(n+255)/256, 256, 0, stream>>>(pos, vel, pos2, feats, n);
  k_rowptr<<<(n+256)/256, 256, 0, stream>>>(ffdst, Eff, bfdst, Ebf, rowff, rowbf, n);
  k_geom<<<(Eff+255)/256, 256, 0, stream>>>(ffsrc, ffdst, pos2, pos2, gff, Eff);
  k_geom<<<(Ebf+255)/256, 256, 0, stream>>>(bfsrc, bfdst, box,  pos2, gbf, Ebf);
  k_layer0<<<(n+3)/4, 256, 0, stream>>>(feats, bfeats, rowff, gff, rowbf, gbf,
                                        W0f, b0f, W0o, b0o, Wd0, bd0, x0, n);
  // layer1: CIN=96
  for (int s = 0; s < n; s += cap1) {
    int rows = (n - s < cap1) ? (n - s) : cap1;
    k_scatter<96><<<rows, 128, 0, stream>>>(x0, rowff, gff, Tbuf, s, rows, n);
    k_gemm_sk<96,KSPLIT><<<dim3((rows+31)/32, KSPLIT), 128, 0, stream>>>(
        Tbuf, Wc1, Wd1, Pbuf, rows, n);
    k_epi<KSPLIT><<<(rows*16+255)/256, 256, 0, stream>>>(
        Pbuf, bc1, bd1, nullptr, h1, x1, s, rows, n);
  }
  // layer2: CIN=64, residual h1
  for (int s = 0; s < n; s += cap2) {
    int rows = (n - s < cap2) ? (n - s) : cap2;
    k_scatter<64><<<rows, 128, 0, stream>>>(x1, rowff, gff, Tbuf, s, rows, n);
    k_gemm_sk<64,KSPLIT><<<dim3((rows+31)/32, KSPLIT), 128, 0, stream>>>(
        Tbuf, Wc2, Wd2, Pbuf, rows, n);
    k_epi<KSPLIT><<<(rows*16+255)/256, 256, 0, stream>>>(
        Pbuf, bc2, bd2, h1, nullptr, x2, s, rows, n);
  }
  // layer3: fused scatter + dot + integrate (no Tbuf roundtrip)
  k_l3fused<<<n, 256, 0, stream>>>(x2, rowff, gff, Wc3, bc3, Wd3, bd3,
                                   pos, pos2, out, n);
}